// Round 16
// baseline (76.225 us; speedup 1.0000x reference)
//
#include <hip/hip_runtime.h>
#include <math.h>

#define K_CODES 512
#define D_DIM   64
#define BM      256        // points per block (4 pt-tiles per wave)
#define NCHUNK  128        // codes per LDS chunk (2 chunks per half)
#define THREADS 256
#define LSTR    72         // padded row stride (ushorts)
#define EPS_GAP 4e-5f      // certified: 2*(dref~8e-6 + dacc~2e-6)=2e-5, 2x margin

// ws layout (bytes): [0,2048) norms | [2048) cnt | [4096,77824) eh presplit
// | [77824,151552) el | [151552,+16n) trip float2[2n] | [+8n) i1 | list
#define WS_CNT_OFF  2048
#define WS_EH_OFF   4096
#define WS_EL_OFF   77824
#define WS_TRIP_OFF 151552

typedef __attribute__((ext_vector_type(8))) short short8v;  // 8 bf16 (4 VGPRs)
typedef __attribute__((ext_vector_type(4))) float f32x4;

// ---------- FROZEN numerics (bit-exact vs np reference since R3) ----------
__device__ __forceinline__ float np_sumsq64(const float* zarr) {
    float L[16];
#pragma unroll
    for (int j = 0; j < 16; ++j)
        L[j] = __fadd_rn(
            __fadd_rn(__fmul_rn(zarr[j],      zarr[j]),
                      __fmul_rn(zarr[j + 16], zarr[j + 16])),
            __fadd_rn(__fmul_rn(zarr[j + 32], zarr[j + 32]),
                      __fmul_rn(zarr[j + 48], zarr[j + 48])));
    float m[8];
#pragma unroll
    for (int j = 0; j < 8; ++j) m[j] = __fadd_rn(L[j], L[j + 8]);
    float n4[4];
#pragma unroll
    for (int j = 0; j < 4; ++j) n4[j] = __fadd_rn(m[j], m[j + 4]);
    return __fadd_rn(__fadd_rn(n4[0], n4[2]), __fadd_rn(n4[1], n4[3]));
}

// ---------- bf16 split helpers (exact: x = hi + lo + r, |r| <= 2^-18|x|) ----------
__device__ __forceinline__ unsigned short f32_bf16_rne(float x) {
    unsigned int u = __float_as_uint(x);
    unsigned int r = (u + 0x7FFFu + ((u >> 16) & 1u)) >> 16;
    return (unsigned short)r;
}
__device__ __forceinline__ float bf16_f32(unsigned short h) {
    return __uint_as_float(((unsigned int)h) << 16);
}
__device__ __forceinline__ void split2(float x, unsigned short& h, unsigned short& l) {
    h = f32_bf16_rne(x);
    l = f32_bf16_rne(x - bf16_f32(h));   // x - hi is exact in fp32
}

// ---------- prep: norms + counter zero + presplit codebook ----------
__global__ __launch_bounds__(256)
void vq_prep_kernel(const float* __restrict__ cb, float* __restrict__ ws,
                    int do_split) {
    int k = blockIdx.x * blockDim.x + threadIdx.x;
    if (k == 0) *reinterpret_cast<int*>((char*)ws + WS_CNT_OFF) = 0;
    if (k >= K_CODES) return;
    float e[D_DIM];
    const float4* p = reinterpret_cast<const float4*>(cb + (size_t)k * D_DIM);
#pragma unroll
    for (int i = 0; i < 16; ++i) {
        float4 v = p[i];
        e[4*i+0]=v.x; e[4*i+1]=v.y; e[4*i+2]=v.z; e[4*i+3]=v.w;
    }
    ws[k] = np_sumsq64(e);
    if (do_split) {
        unsigned short* eh = reinterpret_cast<unsigned short*>((char*)ws + WS_EH_OFF)
                             + (size_t)k * LSTR;
        unsigned short* el = reinterpret_cast<unsigned short*>((char*)ws + WS_EL_OFF)
                             + (size_t)k * LSTR;
#pragma unroll
        for (int i = 0; i < D_DIM; ++i) {
            unsigned short h, l;
            split2(e[i], h, l);
            eh[i] = h; el[i] = l;
        }
#pragma unroll
        for (int i = D_DIM; i < LSTR; ++i) { eh[i] = 0; el[i] = 0; }
    }
}

// ---------- Pass 1 K-SPLIT: 4 ptiles/wave AND 4 waves/SIMD ----------
// R15 lesson: waves = 8192/ptiles is fixed; ptiles=4 gave best per-wave ILP
// and lowest LDS-read count but only 2 waves/SIMD. K-split-2 doubles the
// grid (1024 blocks, 4 blocks/CU at 37.4 KB LDS) -> 4 waves/SIMD with
// ptiles=4 kept. Each half emits exact (m1,m2,i1); merge kernel combines.
__global__ __launch_bounds__(256)
void vq_pass1_ksplit(const float* __restrict__ z,
                     const unsigned short* __restrict__ eh_g,
                     const unsigned short* __restrict__ el_g,
                     const float* __restrict__ norms,
                     float2* __restrict__ trip, int* __restrict__ i1g, int n) {
    __shared__ __align__(16) unsigned short ehS[NCHUNK * LSTR];  // 18 KB
    __shared__ __align__(16) unsigned short elS[NCHUNK * LSTR];  // 18 KB
    __shared__ float nrmL[NCHUNK];                               // 512 B

    const int tid  = threadIdx.x;
    const int l    = tid & 63;
    const int w    = tid >> 6;        // wave 0..3 -> pt-tiles {4w..4w+3}
    const int j    = l >> 4;          // k-chunk / C-row-group selector 0..3
    const int c16  = l & 15;
    const int half = blockIdx.x & 1;              // code half 0/1
    const int base = (blockIdx.x >> 1) * BM;      // point base

    // ---- fire DMA for first chunk of this half ----
    {
        const char* esrc = (const char*)eh_g + (size_t)(half * 2) * (NCHUNK * LSTR * 2);
        const char* lsrc = (const char*)el_g + (size_t)(half * 2) * (NCHUNK * LSTR * 2);
#pragma unroll
        for (int r2 = 0; r2 < 4; ++r2) {
            size_t off = ((size_t)tid + (size_t)r2 * 256) * 16;
            __builtin_amdgcn_global_load_lds(
                (const __attribute__((address_space(1))) void*)(esrc + off),
                (__attribute__((address_space(3))) void*)((char*)ehS + off), 16, 0, 0);
            __builtin_amdgcn_global_load_lds(
                (const __attribute__((address_space(1))) void*)(lsrc + off),
                (__attribute__((address_space(3))) void*)((char*)elS + off), 16, 0, 0);
        }
        if (tid < 128) {
            size_t off = 16384 + (size_t)tid * 16;
            __builtin_amdgcn_global_load_lds(
                (const __attribute__((address_space(1))) void*)(esrc + off),
                (__attribute__((address_space(3))) void*)((char*)ehS + off), 16, 0, 0);
            __builtin_amdgcn_global_load_lds(
                (const __attribute__((address_space(1))) void*)(lsrc + off),
                (__attribute__((address_space(3))) void*)((char*)elS + off), 16, 0, 0);
        }
        if (tid < NCHUNK / 4)
            reinterpret_cast<float4*>(nrmL)[tid] =
                reinterpret_cast<const float4*>(norms)[(half * 2) * (NCHUNK / 4) + tid];
    }

    // ---- z B-fragments direct from global, split in-register (overlaps DMA) ----
    short8v bzh[4][2], bzl[4][2];
#pragma unroll
    for (int p = 0; p < 4; ++p) {
        int row = base + (4 * w + p) * 16 + c16;
        if (row >= n) row = n - 1;
        const float* zp = z + (size_t)row * D_DIM + j * 8;
#pragma unroll
        for (int h = 0; h < 2; ++h) {
            float4 v0 = *reinterpret_cast<const float4*>(zp + h * 32);
            float4 v1 = *reinterpret_cast<const float4*>(zp + h * 32 + 4);
            unsigned short hh[8], ll[8];
            split2(v0.x, hh[0], ll[0]); split2(v0.y, hh[1], ll[1]);
            split2(v0.z, hh[2], ll[2]); split2(v0.w, hh[3], ll[3]);
            split2(v1.x, hh[4], ll[4]); split2(v1.y, hh[5], ll[5]);
            split2(v1.z, hh[6], ll[6]); split2(v1.w, hh[7], ll[7]);
            short8v th, tl;
#pragma unroll
            for (int i = 0; i < 8; ++i) { th[i] = (short)hh[i]; tl[i] = (short)ll[i]; }
            bzh[p][h] = th; bzl[p][h] = tl;
        }
    }

    float m1[4] = {INFINITY, INFINITY, INFINITY, INFINITY};
    float m2[4] = {INFINITY, INFINITY, INFINITY, INFINITY};
    int   i1[4] = {0, 0, 0, 0};

    for (int c = 0; c < 2; ++c) {
        if (c > 0) {
            __syncthreads();   // all waves done reading buffer
            const char* esrc = (const char*)eh_g + (size_t)(half * 2 + c) * (NCHUNK * LSTR * 2);
            const char* lsrc = (const char*)el_g + (size_t)(half * 2 + c) * (NCHUNK * LSTR * 2);
#pragma unroll
            for (int r2 = 0; r2 < 4; ++r2) {
                size_t off = ((size_t)tid + (size_t)r2 * 256) * 16;
                __builtin_amdgcn_global_load_lds(
                    (const __attribute__((address_space(1))) void*)(esrc + off),
                    (__attribute__((address_space(3))) void*)((char*)ehS + off), 16, 0, 0);
                __builtin_amdgcn_global_load_lds(
                    (const __attribute__((address_space(1))) void*)(lsrc + off),
                    (__attribute__((address_space(3))) void*)((char*)elS + off), 16, 0, 0);
            }
            if (tid < 128) {
                size_t off = 16384 + (size_t)tid * 16;
                __builtin_amdgcn_global_load_lds(
                    (const __attribute__((address_space(1))) void*)(esrc + off),
                    (__attribute__((address_space(3))) void*)((char*)ehS + off), 16, 0, 0);
                __builtin_amdgcn_global_load_lds(
                    (const __attribute__((address_space(1))) void*)(lsrc + off),
                    (__attribute__((address_space(3))) void*)((char*)elS + off), 16, 0, 0);
            }
            if (tid < NCHUNK / 4)
                reinterpret_cast<float4*>(nrmL)[tid] =
                    reinterpret_cast<const float4*>(norms)[(half * 2 + c) * (NCHUNK / 4) + tid];
        }
        __syncthreads();   // DMA drained (compiler emits vmcnt(0) before barrier)

#pragma unroll
        for (int ct = 0; ct < 8; ++ct) {
            int ar = (ct * 16 + c16) * LSTR + j * 8;
            short8v aeh0 = *reinterpret_cast<const short8v*>(&ehS[ar]);
            short8v aeh1 = *reinterpret_cast<const short8v*>(&ehS[ar + 32]);
            short8v ael0 = *reinterpret_cast<const short8v*>(&elS[ar]);
            short8v ael1 = *reinterpret_cast<const short8v*>(&elS[ar + 32]);
            float4 nr = *reinterpret_cast<const float4*>(&nrmL[ct * 16 + j * 4]);
            float nra[4] = {nr.x, nr.y, nr.z, nr.w};
            int kg0 = half * 256 + c * NCHUNK + ct * 16 + j * 4;
#pragma unroll
            for (int p = 0; p < 4; ++p) {
                f32x4 acc = {0.f, 0.f, 0.f, 0.f};
                acc = __builtin_amdgcn_mfma_f32_16x16x32_bf16(aeh0, bzh[p][0], acc, 0, 0, 0);
                acc = __builtin_amdgcn_mfma_f32_16x16x32_bf16(aeh1, bzh[p][1], acc, 0, 0, 0);
                acc = __builtin_amdgcn_mfma_f32_16x16x32_bf16(aeh0, bzl[p][0], acc, 0, 0, 0);
                acc = __builtin_amdgcn_mfma_f32_16x16x32_bf16(aeh1, bzl[p][1], acc, 0, 0, 0);
                acc = __builtin_amdgcn_mfma_f32_16x16x32_bf16(ael0, bzh[p][0], acc, 0, 0, 0);
                acc = __builtin_amdgcn_mfma_f32_16x16x32_bf16(ael1, bzh[p][1], acc, 0, 0, 0);
#pragma unroll
                for (int r = 0; r < 4; ++r) {
                    float s = fmaf(-2.0f, acc[r], nra[r]);   // accuracy-only path
                    int kg = kg0 + r;
                    bool lt1 = s < m1[p];
                    float nm2 = lt1 ? m1[p] : fminf(s, m2[p]);
                    i1[p] = lt1 ? kg : i1[p];
                    m1[p] = lt1 ? s : m1[p];
                    m2[p] = nm2;
                }
            }
        }
    }

    // ---- butterfly merge across row-groups; write per-half triple ----
#pragma unroll
    for (int p = 0; p < 4; ++p) {
        float a1 = m1[p], a2 = m2[p]; int ai = i1[p];
#pragma unroll
        for (int off = 16; off <= 32; off <<= 1) {
            float o1 = __shfl_xor(a1, off, 64);
            float o2 = __shfl_xor(a2, off, 64);
            int   oi = __shfl_xor(ai, off, 64);
            float hi = fmaxf(a1, o1);
            bool take = o1 < a1;                 // exact tie => flagged by merge anyway
            ai = take ? oi : ai;
            a1 = take ? o1 : a1;
            a2 = fminf(hi, fminf(a2, o2));
        }
        int pt = base + (4 * w + p) * 16 + c16;
        if (j == 0 && pt < n) {
            trip[2 * pt + half] = make_float2(a1, a2);
            i1g[2 * pt + half]  = ai;
        }
    }
}

// ---------- Merge: combine the two halves' triples; flag + compact ----------
__global__ __launch_bounds__(256)
void vq_merge_kernel(const float2* __restrict__ trip, const int* __restrict__ i1g,
                     int* __restrict__ out, int* __restrict__ cnt,
                     int* __restrict__ list, int cap, int n) {
    int t = blockIdx.x * 256 + threadIdx.x;
    int lane = threadIdx.x & 63;
    bool valid = (t < n);
    float m1 = INFINITY, m2 = INFINITY; int ig = 0;
    if (valid) {
        float2 a = trip[2 * t + 0], b = trip[2 * t + 1];
        int ia = i1g[2 * t + 0],   ib = i1g[2 * t + 1];
        bool bwin = b.x < a.x;               // tie -> half0 (lower k indices)
        m1 = bwin ? b.x : a.x;
        ig = bwin ? ib  : ia;
        float loser = bwin ? a.x : b.x;
        float wm2   = bwin ? b.y : a.y;
        m2 = fminf(loser, wm2);              // global second-best
    }
    bool flag = valid && (m2 - m1 <= EPS_GAP);
    unsigned long long m = __ballot(flag);
    int abase = 0;
    if (m) {
        int leader = __ffsll(m) - 1;
        if (lane == leader) abase = atomicAdd(cnt, __popcll(m));
        abase = __shfl(abase, leader, 64);
    }
    if (valid) {
        int val = ig;
        if (flag) {
            int rank = __popcll(m & ((1ull << lane) - 1ull));
            int slot = abase + rank;
            if (slot < cap) list[slot] = t;
            else            val |= (int)0x80000000;   // overflow fallback
        }
        out[t] = val;
    }
}

// ---------- Pass 1 LEGACY (R13 verbatim, BM=128): used only if ws too small ----------
__global__ __launch_bounds__(256)
void vq_pass1_legacy(const float* __restrict__ z, const float* __restrict__ cb,
                     const float* __restrict__ norms, int* __restrict__ out,
                     int* __restrict__ cnt, int* __restrict__ list, int cap, int n) {
    __shared__ unsigned short zhS[128 * LSTR];
    __shared__ unsigned short zlS[128 * LSTR];
    __shared__ unsigned short ehS[NCHUNK * LSTR];
    __shared__ unsigned short elS[NCHUNK * LSTR];
    __shared__ float nrmL[NCHUNK];

    const int tid  = threadIdx.x;
    const int l    = tid & 63;
    const int w    = tid >> 6;
    const int j    = l >> 4;
    const int c16  = l & 15;
    const int base = blockIdx.x * 128;

    const float4* z4 = reinterpret_cast<const float4*>(z);
#pragma unroll
    for (int rep = 0; rep < 8; ++rep) {
        int flat = rep * THREADS + tid;
        int pt   = flat >> 4;
        int dblk = flat & 15;
        int gp = base + pt; if (gp >= n) gp = n - 1;
        float4 v = z4[(size_t)gp * 16 + dblk];
        ushort4 h, lo;
        split2(v.x, h.x, lo.x); split2(v.y, h.y, lo.y);
        split2(v.z, h.z, lo.z); split2(v.w, h.w, lo.w);
        *reinterpret_cast<ushort4*>(&zhS[pt * LSTR + dblk * 4]) = h;
        *reinterpret_cast<ushort4*>(&zlS[pt * LSTR + dblk * 4]) = lo;
    }
    __syncthreads();

    short8v bzh[2][2], bzl[2][2];
#pragma unroll
    for (int p = 0; p < 2; ++p) {
        int pr = ((2 * w + p) * 16 + c16) * LSTR;
#pragma unroll
        for (int h = 0; h < 2; ++h) {
            int off = pr + h * 32 + j * 8;
            bzh[p][h] = *reinterpret_cast<const short8v*>(&zhS[off]);
            bzl[p][h] = *reinterpret_cast<const short8v*>(&zlS[off]);
        }
    }

    float m1[2] = {INFINITY, INFINITY};
    float m2[2] = {INFINITY, INFINITY};
    int   i1[2] = {0, 0};

    for (int c = 0; c < 4; ++c) {
        __syncthreads();
        const float4* cb4 = reinterpret_cast<const float4*>(cb);
#pragma unroll
        for (int rep = 0; rep < 8; ++rep) {
            int flat = rep * THREADS + tid;
            int code = flat >> 4;
            int dblk = flat & 15;
            float4 v = cb4[(size_t)(c * NCHUNK + code) * 16 + dblk];
            ushort4 h, lo;
            split2(v.x, h.x, lo.x); split2(v.y, h.y, lo.y);
            split2(v.z, h.z, lo.z); split2(v.w, h.w, lo.w);
            *reinterpret_cast<ushort4*>(&ehS[code * LSTR + dblk * 4]) = h;
            *reinterpret_cast<ushort4*>(&elS[code * LSTR + dblk * 4]) = lo;
        }
        if (tid < NCHUNK / 4)
            reinterpret_cast<float4*>(nrmL)[tid] =
                reinterpret_cast<const float4*>(norms)[c * (NCHUNK / 4) + tid];
        __syncthreads();

#pragma unroll
        for (int ct = 0; ct < 8; ++ct) {
            int ar = (ct * 16 + c16) * LSTR + j * 8;
            short8v aeh0 = *reinterpret_cast<const short8v*>(&ehS[ar]);
            short8v aeh1 = *reinterpret_cast<const short8v*>(&ehS[ar + 32]);
            short8v ael0 = *reinterpret_cast<const short8v*>(&elS[ar]);
            short8v ael1 = *reinterpret_cast<const short8v*>(&elS[ar + 32]);
            float4 nr = *reinterpret_cast<const float4*>(&nrmL[ct * 16 + j * 4]);
            float nra[4] = {nr.x, nr.y, nr.z, nr.w};
            int kg0 = c * NCHUNK + ct * 16 + j * 4;
#pragma unroll
            for (int p = 0; p < 2; ++p) {
                f32x4 acc = {0.f, 0.f, 0.f, 0.f};
                acc = __builtin_amdgcn_mfma_f32_16x16x32_bf16(aeh0, bzh[p][0], acc, 0, 0, 0);
                acc = __builtin_amdgcn_mfma_f32_16x16x32_bf16(aeh1, bzh[p][1], acc, 0, 0, 0);
                acc = __builtin_amdgcn_mfma_f32_16x16x32_bf16(aeh0, bzl[p][0], acc, 0, 0, 0);
                acc = __builtin_amdgcn_mfma_f32_16x16x32_bf16(aeh1, bzl[p][1], acc, 0, 0, 0);
                acc = __builtin_amdgcn_mfma_f32_16x16x32_bf16(ael0, bzh[p][0], acc, 0, 0, 0);
                acc = __builtin_amdgcn_mfma_f32_16x16x32_bf16(ael1, bzh[p][1], acc, 0, 0, 0);
#pragma unroll
                for (int r = 0; r < 4; ++r) {
                    float s = fmaf(-2.0f, acc[r], nra[r]);
                    int kg = kg0 + r;
                    bool lt1 = s < m1[p];
                    float nm2 = lt1 ? m1[p] : fminf(s, m2[p]);
                    i1[p] = lt1 ? kg : i1[p];
                    m1[p] = lt1 ? s : m1[p];
                    m2[p] = nm2;
                }
            }
        }
    }

#pragma unroll
    for (int p = 0; p < 2; ++p) {
        float a1 = m1[p], a2 = m2[p]; int ai = i1[p];
#pragma unroll
        for (int off = 16; off <= 32; off <<= 1) {
            float o1 = __shfl_xor(a1, off, 64);
            float o2 = __shfl_xor(a2, off, 64);
            int   oi = __shfl_xor(ai, off, 64);
            float hi = fmaxf(a1, o1);
            bool take = o1 < a1;
            ai = take ? oi : ai;
            a1 = take ? o1 : a1;
            a2 = fminf(hi, fminf(a2, o2));
        }
        int  ptg    = base + (2 * w + p) * 16 + c16;
        bool writer = (j == 0) && (ptg < n);
        bool flag   = writer && (a2 - a1 <= EPS_GAP);
        unsigned long long m = __ballot(flag);
        int abase = 0;
        if (m) {
            int leader = __ffsll(m) - 1;
            if (l == leader) abase = atomicAdd(cnt, __popcll(m));
            abase = __shfl(abase, leader, 64);
        }
        if (writer) {
            int val = ai;
            if (flag) {
                int rank = __popcll(m & ((1ull << l) - 1ull));
                int slot = abase + rank;
                if (slot < cap) list[slot] = ptg;
                else            val |= (int)0x80000000;
            }
            out[ptg] = val;
        }
    }
}

// ---------- Cleanup: one wave per flagged point (grid-strided worklist) ----------
__device__ __forceinline__ void vq_rescan_point(
        const float* __restrict__ z, const float* __restrict__ cb,
        const float* __restrict__ norms, int* __restrict__ out,
        int pt, int lane) {
    float zr[D_DIM];
    const float4* zp = reinterpret_cast<const float4*>(z + (size_t)pt * D_DIM);
#pragma unroll
    for (int i = 0; i < 16; ++i) {
        float4 q = zp[i];
        zr[4*i+0]=q.x; zr[4*i+1]=q.y; zr[4*i+2]=q.z; zr[4*i+3]=q.w;
    }
    const float sz = np_sumsq64(zr);           // FROZEN tree
    float best = INFINITY; int bi = 0x7FFFFFFF;
#pragma unroll 1
    for (int r = 0; r < 8; ++r) {              // 8 codes/lane, SEQUENTIAL (no spill)
        const float4* e4 = reinterpret_cast<const float4*>(cb) +
                           ((size_t)(lane * 8 + r) << 4);
        float a = 0.f;
#pragma unroll
        for (int g = 0; g < 16; ++g) {         // FROZEN ascending-d chain
            float4 q = e4[g];
            a = fmaf(zr[4*g+0], q.x, a);
            a = fmaf(zr[4*g+1], q.y, a);
            a = fmaf(zr[4*g+2], q.z, a);
            a = fmaf(zr[4*g+3], q.w, a);
        }
        float s = __fadd_rn(__fsub_rn(sz, __fmul_rn(2.0f, a)),
                            norms[lane * 8 + r]);
        if (s < best) { best = s; bi = lane * 8 + r; }
    }
#pragma unroll
    for (int off = 1; off < 64; off <<= 1) {   // (value, index) first-min reduce
        float os = __shfl_xor(best, off, 64);
        int   ok = __shfl_xor(bi, off, 64);
        if (os < best || (os == best && ok < bi)) { best = os; bi = ok; }
    }
    if (lane == 0) out[pt] = bi;
}

__global__ __launch_bounds__(256)
void vq_cleanup_kernel(const float* __restrict__ z, const float* __restrict__ cb,
                       const float* __restrict__ norms,
                       const int* __restrict__ cnt, const int* __restrict__ list,
                       int cap, int* __restrict__ out, int n) {
    const int lane   = threadIdx.x & 63;
    const int wid    = (blockIdx.x * blockDim.x + threadIdx.x) >> 6;
    const int nwaves = (gridDim.x * blockDim.x) >> 6;

    int total = *cnt;
    int lim   = total < cap ? total : cap;
    for (int i = wid; i < lim; i += nwaves)
        vq_rescan_point(z, cb, norms, out, list[i], lane);

    if (total > cap) {   // overflow fallback: scan out[] for bit-31 flags
        for (int b = wid * 64; b < n; b += nwaves * 64) {
            int t = b + lane;
            int v = (t < n) ? out[t] : 0;
            unsigned long long m = __ballot(v < 0);
            while (m) {
                int bb = __ffsll(m) - 1;
                m &= m - 1ull;
                vq_rescan_point(z, cb, norms, out, b + bb, lane);
            }
        }
    }
}

extern "C" void kernel_launch(void* const* d_in, const int* in_sizes, int n_in,
                              void* d_out, int out_size, void* d_ws, size_t ws_size,
                              hipStream_t stream) {
    const float* z  = (const float*)d_in[0];
    const float* cb = (const float*)d_in[1];
    int n = in_sizes[0] / D_DIM;           // 131072 points
    float* norms = (float*)d_ws;
    int*   cnt   = (int*)((char*)d_ws + WS_CNT_OFF);
    int* out = (int*)d_out;

    size_t trip_bytes = (size_t)n * 16;    // float2[2n]
    size_t i1_bytes   = (size_t)n * 8;     // int[2n]
    size_t i1_off     = WS_TRIP_OFF + trip_bytes;
    size_t list_off   = i1_off + i1_bytes;
    bool fast = ws_size >= list_off + 4096;

    vq_prep_kernel<<<(K_CODES + 255) / 256, 256, 0, stream>>>(cb, norms, fast ? 1 : 0);

    if (fast) {
        const unsigned short* eh = (const unsigned short*)((char*)d_ws + WS_EH_OFF);
        const unsigned short* el = (const unsigned short*)((char*)d_ws + WS_EL_OFF);
        float2* trip = (float2*)((char*)d_ws + WS_TRIP_OFF);
        int*    i1g  = (int*)((char*)d_ws + i1_off);
        int*    list = (int*)((char*)d_ws + list_off);
        int     cap  = (int)((ws_size - list_off) / 4);
        int nblk = (n + BM - 1) / BM;
        vq_pass1_ksplit<<<2 * nblk, THREADS, 0, stream>>>(z, eh, el, norms, trip, i1g, n);
        vq_merge_kernel<<<(n + 255) / 256, 256, 0, stream>>>(trip, i1g, out, cnt, list, cap, n);
        vq_cleanup_kernel<<<512, 256, 0, stream>>>(z, cb, norms, cnt, list, cap, out, n);
    } else {
        int* list = (int*)d_ws + 513;
        int  cap  = (int)(ws_size / 4) - 513; if (cap < 0) cap = 0;
        vq_pass1_legacy<<<(n + 127) / 128, THREADS, 0, stream>>>(
            z, cb, norms, out, cnt, list, cap, n);
        vq_cleanup_kernel<<<512, 256, 0, stream>>>(z, cb, norms, cnt, list, cap, out, n);
    }
}

// Round 17
// 75.491 us; speedup vs baseline: 1.0097x; 1.0097x over previous
//
#include <hip/hip_runtime.h>
#include <math.h>

#define K_CODES 512
#define D_DIM   64
#define BM      256        // points per block (4 pt-tiles per wave)
#define THREADS 256
#define LSTR    72         // padded presplit row stride (ushorts); row = 144 B (16B-aligned)
#define EPS_GAP 4e-5f      // certified: 2*(dref~8e-6 + dacc~2e-6)=2e-5, 2x margin

// ws layout (bytes): [0,2048) norms | [2048) cnt | [4096,77824) eh presplit
// bf16 [512][72] | [77824,151552) el | [151552,..) worklist
#define WS_CNT_OFF  2048
#define WS_EH_OFF   4096
#define WS_EL_OFF   77824
#define WS_LIST_OFF 151552

typedef __attribute__((ext_vector_type(8))) short short8v;  // 8 bf16 (4 VGPRs)
typedef __attribute__((ext_vector_type(4))) float f32x4;

// ---------- FROZEN numerics (bit-exact vs np reference since R3) ----------
__device__ __forceinline__ float np_sumsq64(const float* zarr) {
    float L[16];
#pragma unroll
    for (int j = 0; j < 16; ++j)
        L[j] = __fadd_rn(
            __fadd_rn(__fmul_rn(zarr[j],      zarr[j]),
                      __fmul_rn(zarr[j + 16], zarr[j + 16])),
            __fadd_rn(__fmul_rn(zarr[j + 32], zarr[j + 32]),
                      __fmul_rn(zarr[j + 48], zarr[j + 48])));
    float m[8];
#pragma unroll
    for (int j = 0; j < 8; ++j) m[j] = __fadd_rn(L[j], L[j + 8]);
    float n4[4];
#pragma unroll
    for (int j = 0; j < 4; ++j) n4[j] = __fadd_rn(m[j], m[j + 4]);
    return __fadd_rn(__fadd_rn(n4[0], n4[2]), __fadd_rn(n4[1], n4[3]));
}

// ---------- bf16 split helpers (exact: x = hi + lo + r, |r| <= 2^-18|x|) ----------
__device__ __forceinline__ unsigned short f32_bf16_rne(float x) {
    unsigned int u = __float_as_uint(x);
    unsigned int r = (u + 0x7FFFu + ((u >> 16) & 1u)) >> 16;
    return (unsigned short)r;
}
__device__ __forceinline__ float bf16_f32(unsigned short h) {
    return __uint_as_float(((unsigned int)h) << 16);
}
__device__ __forceinline__ void split2(float x, unsigned short& h, unsigned short& l) {
    h = f32_bf16_rne(x);
    l = f32_bf16_rne(x - bf16_f32(h));   // x - hi is exact in fp32
}

// ---------- prep: norms + counter zero + presplit codebook ----------
__global__ __launch_bounds__(256)
void vq_prep_kernel(const float* __restrict__ cb, float* __restrict__ ws,
                    int do_split) {
    int k = blockIdx.x * blockDim.x + threadIdx.x;
    if (k == 0) *reinterpret_cast<int*>((char*)ws + WS_CNT_OFF) = 0;
    if (k >= K_CODES) return;
    float e[D_DIM];
    const float4* p = reinterpret_cast<const float4*>(cb + (size_t)k * D_DIM);
#pragma unroll
    for (int i = 0; i < 16; ++i) {
        float4 v = p[i];
        e[4*i+0]=v.x; e[4*i+1]=v.y; e[4*i+2]=v.z; e[4*i+3]=v.w;
    }
    ws[k] = np_sumsq64(e);
    if (do_split) {
        unsigned short* eh = reinterpret_cast<unsigned short*>((char*)ws + WS_EH_OFF)
                             + (size_t)k * LSTR;
        unsigned short* el = reinterpret_cast<unsigned short*>((char*)ws + WS_EL_OFF)
                             + (size_t)k * LSTR;
#pragma unroll
        for (int i = 0; i < D_DIM; ++i) {
            unsigned short h, l;
            split2(e[i], h, l);
            eh[i] = h; el[i] = l;
        }
#pragma unroll
        for (int i = D_DIM; i < LSTR; ++i) { eh[i] = 0; el[i] = 0; }
    }
}

// ---------- Pass 1 STREAM: no LDS, no barriers; code-frags direct from L2 ----------
// R13-R16 evidence: every variant of the {DMA->barrier->LDS-read->MFMA->barrier}
// phase structure lands at 40+-4us vs a ~10us issue floor (occupancy/dbuf/
// K-split all null) — the structure IS the ceiling (m97 lesson). The presplit
// codebook is 147 KB = permanently L2-resident, so stream A-frags straight
// from global (4 x dwordx4 per ct, induction-simple addresses, unroll 8) with
// ZERO barriers after the prologue — nothing ever drains the vmem queue.
// Live set ~124 VGPR (z-frags 64, proven no-spill in R14). MFMA inputs
// bit-identical to R14 (same presplit bytes, same order).
__global__ __launch_bounds__(256)
void vq_pass1_stream(const float* __restrict__ z,
                     const unsigned short* __restrict__ eh_g,
                     const unsigned short* __restrict__ el_g,
                     const float* __restrict__ norms, int* __restrict__ out,
                     int* __restrict__ cnt, int* __restrict__ list, int cap, int n) {
    const int tid  = threadIdx.x;
    const int l    = tid & 63;
    const int w    = tid >> 6;        // wave 0..3 -> pt-tiles {4w..4w+3}
    const int j    = l >> 4;          // k-chunk / C-row-group selector 0..3
    const int c16  = l & 15;
    const int base = blockIdx.x * BM;

    // ---- z B-fragments direct from global, split in-register (one-time) ----
    short8v bzh[4][2], bzl[4][2];
#pragma unroll
    for (int p = 0; p < 4; ++p) {
        int row = base + (4 * w + p) * 16 + c16;
        if (row >= n) row = n - 1;
        const float* zp = z + (size_t)row * D_DIM + j * 8;
#pragma unroll
        for (int h = 0; h < 2; ++h) {
            float4 v0 = *reinterpret_cast<const float4*>(zp + h * 32);
            float4 v1 = *reinterpret_cast<const float4*>(zp + h * 32 + 4);
            unsigned short hh[8], ll[8];
            split2(v0.x, hh[0], ll[0]); split2(v0.y, hh[1], ll[1]);
            split2(v0.z, hh[2], ll[2]); split2(v0.w, hh[3], ll[3]);
            split2(v1.x, hh[4], ll[4]); split2(v1.y, hh[5], ll[5]);
            split2(v1.z, hh[6], ll[6]); split2(v1.w, hh[7], ll[7]);
            short8v th, tl;
#pragma unroll
            for (int i = 0; i < 8; ++i) { th[i] = (short)hh[i]; tl[i] = (short)ll[i]; }
            bzh[p][h] = th; bzl[p][h] = tl;
        }
    }

    float m1[4] = {INFINITY, INFINITY, INFINITY, INFINITY};
    float m2[4] = {INFINITY, INFINITY, INFINITY, INFINITY};
    int   i1[4] = {0, 0, 0, 0};

    // ---- 32 ct-tiles, straight-line, barrier-free ----
#pragma unroll 8
    for (int ct = 0; ct < 32; ++ct) {
        const unsigned short* er = eh_g + (size_t)(ct * 16 + c16) * LSTR + j * 8;
        const unsigned short* lr = el_g + (size_t)(ct * 16 + c16) * LSTR + j * 8;
        short8v aeh0 = *reinterpret_cast<const short8v*>(er);
        short8v aeh1 = *reinterpret_cast<const short8v*>(er + 32);
        short8v ael0 = *reinterpret_cast<const short8v*>(lr);
        short8v ael1 = *reinterpret_cast<const short8v*>(lr + 32);
        float4 nr = *reinterpret_cast<const float4*>(norms + ct * 16 + j * 4);
        float nra[4] = {nr.x, nr.y, nr.z, nr.w};
        int kg0 = ct * 16 + j * 4;
#pragma unroll
        for (int p = 0; p < 4; ++p) {
            f32x4 acc = {0.f, 0.f, 0.f, 0.f};
            acc = __builtin_amdgcn_mfma_f32_16x16x32_bf16(aeh0, bzh[p][0], acc, 0, 0, 0);
            acc = __builtin_amdgcn_mfma_f32_16x16x32_bf16(aeh1, bzh[p][1], acc, 0, 0, 0);
            acc = __builtin_amdgcn_mfma_f32_16x16x32_bf16(aeh0, bzl[p][0], acc, 0, 0, 0);
            acc = __builtin_amdgcn_mfma_f32_16x16x32_bf16(aeh1, bzl[p][1], acc, 0, 0, 0);
            acc = __builtin_amdgcn_mfma_f32_16x16x32_bf16(ael0, bzh[p][0], acc, 0, 0, 0);
            acc = __builtin_amdgcn_mfma_f32_16x16x32_bf16(ael1, bzh[p][1], acc, 0, 0, 0);
#pragma unroll
            for (int r = 0; r < 4; ++r) {
                float s = fmaf(-2.0f, acc[r], nra[r]);   // accuracy-only path
                int kg = kg0 + r;
                bool lt1 = s < m1[p];
                float nm2 = lt1 ? m1[p] : fminf(s, m2[p]);
                i1[p] = lt1 ? kg : i1[p];
                m1[p] = lt1 ? s : m1[p];
                m2[p] = nm2;
            }
        }
    }

    // ---- butterfly merge (pure shfl) + compacting store ----
#pragma unroll
    for (int p = 0; p < 4; ++p) {
        float a1 = m1[p], a2 = m2[p]; int ai = i1[p];
#pragma unroll
        for (int off = 16; off <= 32; off <<= 1) {
            float o1 = __shfl_xor(a1, off, 64);
            float o2 = __shfl_xor(a2, off, 64);
            int   oi = __shfl_xor(ai, off, 64);
            float hi = fmaxf(a1, o1);
            bool take = o1 < a1;                 // ties keep own (tie => flagged anyway)
            ai = take ? oi : ai;
            a1 = take ? o1 : a1;
            a2 = fminf(hi, fminf(a2, o2));
        }
        int  ptg    = base + (4 * w + p) * 16 + c16;
        bool writer = (j == 0) && (ptg < n);
        bool flag   = writer && (a2 - a1 <= EPS_GAP);
        unsigned long long m = __ballot(flag);
        int abase = 0;
        if (m) {
            int leader = __ffsll(m) - 1;
            if (l == leader) abase = atomicAdd(cnt, __popcll(m));
            abase = __shfl(abase, leader, 64);
        }
        if (writer) {
            int val = ai;
            if (flag) {
                int rank = __popcll(m & ((1ull << l) - 1ull));
                int slot = abase + rank;
                if (slot < cap) list[slot] = ptg;       // worklist path
                else            val |= (int)0x80000000; // overflow fallback
            }
            out[ptg] = val;
        }
    }
}

// ---------- Pass 1 LEGACY (R13 verbatim, BM=128): used only if ws too small ----------
__global__ __launch_bounds__(256)
void vq_pass1_legacy(const float* __restrict__ z, const float* __restrict__ cb,
                     const float* __restrict__ norms, int* __restrict__ out,
                     int* __restrict__ cnt, int* __restrict__ list, int cap, int n) {
    __shared__ unsigned short zhS[128 * LSTR];
    __shared__ unsigned short zlS[128 * LSTR];
    __shared__ unsigned short ehS[128 * LSTR];
    __shared__ unsigned short elS[128 * LSTR];
    __shared__ float nrmL[128];

    const int tid  = threadIdx.x;
    const int l    = tid & 63;
    const int w    = tid >> 6;
    const int j    = l >> 4;
    const int c16  = l & 15;
    const int base = blockIdx.x * 128;

    const float4* z4 = reinterpret_cast<const float4*>(z);
#pragma unroll
    for (int rep = 0; rep < 8; ++rep) {
        int flat = rep * THREADS + tid;
        int pt   = flat >> 4;
        int dblk = flat & 15;
        int gp = base + pt; if (gp >= n) gp = n - 1;
        float4 v = z4[(size_t)gp * 16 + dblk];
        ushort4 h, lo;
        split2(v.x, h.x, lo.x); split2(v.y, h.y, lo.y);
        split2(v.z, h.z, lo.z); split2(v.w, h.w, lo.w);
        *reinterpret_cast<ushort4*>(&zhS[pt * LSTR + dblk * 4]) = h;
        *reinterpret_cast<ushort4*>(&zlS[pt * LSTR + dblk * 4]) = lo;
    }
    __syncthreads();

    short8v bzh[2][2], bzl[2][2];
#pragma unroll
    for (int p = 0; p < 2; ++p) {
        int pr = ((2 * w + p) * 16 + c16) * LSTR;
#pragma unroll
        for (int h = 0; h < 2; ++h) {
            int off = pr + h * 32 + j * 8;
            bzh[p][h] = *reinterpret_cast<const short8v*>(&zhS[off]);
            bzl[p][h] = *reinterpret_cast<const short8v*>(&zlS[off]);
        }
    }

    float m1[2] = {INFINITY, INFINITY};
    float m2[2] = {INFINITY, INFINITY};
    int   i1[2] = {0, 0};

    for (int c = 0; c < 4; ++c) {
        __syncthreads();
        const float4* cb4 = reinterpret_cast<const float4*>(cb);
#pragma unroll
        for (int rep = 0; rep < 8; ++rep) {
            int flat = rep * THREADS + tid;
            int code = flat >> 4;
            int dblk = flat & 15;
            float4 v = cb4[(size_t)(c * 128 + code) * 16 + dblk];
            ushort4 h, lo;
            split2(v.x, h.x, lo.x); split2(v.y, h.y, lo.y);
            split2(v.z, h.z, lo.z); split2(v.w, h.w, lo.w);
            *reinterpret_cast<ushort4*>(&ehS[code * LSTR + dblk * 4]) = h;
            *reinterpret_cast<ushort4*>(&elS[code * LSTR + dblk * 4]) = lo;
        }
        if (tid < 32)
            reinterpret_cast<float4*>(nrmL)[tid] =
                reinterpret_cast<const float4*>(norms)[c * 32 + tid];
        __syncthreads();

#pragma unroll
        for (int ct = 0; ct < 8; ++ct) {
            int ar = (ct * 16 + c16) * LSTR + j * 8;
            short8v aeh0 = *reinterpret_cast<const short8v*>(&ehS[ar]);
            short8v aeh1 = *reinterpret_cast<const short8v*>(&ehS[ar + 32]);
            short8v ael0 = *reinterpret_cast<const short8v*>(&elS[ar]);
            short8v ael1 = *reinterpret_cast<const short8v*>(&elS[ar + 32]);
            float4 nr = *reinterpret_cast<const float4*>(&nrmL[ct * 16 + j * 4]);
            float nra[4] = {nr.x, nr.y, nr.z, nr.w};
            int kg0 = c * 128 + ct * 16 + j * 4;
#pragma unroll
            for (int p = 0; p < 2; ++p) {
                f32x4 acc = {0.f, 0.f, 0.f, 0.f};
                acc = __builtin_amdgcn_mfma_f32_16x16x32_bf16(aeh0, bzh[p][0], acc, 0, 0, 0);
                acc = __builtin_amdgcn_mfma_f32_16x16x32_bf16(aeh1, bzh[p][1], acc, 0, 0, 0);
                acc = __builtin_amdgcn_mfma_f32_16x16x32_bf16(aeh0, bzl[p][0], acc, 0, 0, 0);
                acc = __builtin_amdgcn_mfma_f32_16x16x32_bf16(aeh1, bzl[p][1], acc, 0, 0, 0);
                acc = __builtin_amdgcn_mfma_f32_16x16x32_bf16(ael0, bzh[p][0], acc, 0, 0, 0);
                acc = __builtin_amdgcn_mfma_f32_16x16x32_bf16(ael1, bzh[p][1], acc, 0, 0, 0);
#pragma unroll
                for (int r = 0; r < 4; ++r) {
                    float s = fmaf(-2.0f, acc[r], nra[r]);
                    int kg = kg0 + r;
                    bool lt1 = s < m1[p];
                    float nm2 = lt1 ? m1[p] : fminf(s, m2[p]);
                    i1[p] = lt1 ? kg : i1[p];
                    m1[p] = lt1 ? s : m1[p];
                    m2[p] = nm2;
                }
            }
        }
    }

#pragma unroll
    for (int p = 0; p < 2; ++p) {
        float a1 = m1[p], a2 = m2[p]; int ai = i1[p];
#pragma unroll
        for (int off = 16; off <= 32; off <<= 1) {
            float o1 = __shfl_xor(a1, off, 64);
            float o2 = __shfl_xor(a2, off, 64);
            int   oi = __shfl_xor(ai, off, 64);
            float hi = fmaxf(a1, o1);
            bool take = o1 < a1;
            ai = take ? oi : ai;
            a1 = take ? o1 : a1;
            a2 = fminf(hi, fminf(a2, o2));
        }
        int  ptg    = base + (2 * w + p) * 16 + c16;
        bool writer = (j == 0) && (ptg < n);
        bool flag   = writer && (a2 - a1 <= EPS_GAP);
        unsigned long long m = __ballot(flag);
        int abase = 0;
        if (m) {
            int leader = __ffsll(m) - 1;
            if (l == leader) abase = atomicAdd(cnt, __popcll(m));
            abase = __shfl(abase, leader, 64);
        }
        if (writer) {
            int val = ai;
            if (flag) {
                int rank = __popcll(m & ((1ull << l) - 1ull));
                int slot = abase + rank;
                if (slot < cap) list[slot] = ptg;
                else            val |= (int)0x80000000;
            }
            out[ptg] = val;
        }
    }
}

// ---------- Pass 2: one wave per flagged point (grid-strided worklist) ----------
__device__ __forceinline__ void vq_rescan_point(
        const float* __restrict__ z, const float* __restrict__ cb,
        const float* __restrict__ norms, int* __restrict__ out,
        int pt, int lane) {
    float zr[D_DIM];
    const float4* zp = reinterpret_cast<const float4*>(z + (size_t)pt * D_DIM);
#pragma unroll
    for (int i = 0; i < 16; ++i) {
        float4 q = zp[i];
        zr[4*i+0]=q.x; zr[4*i+1]=q.y; zr[4*i+2]=q.z; zr[4*i+3]=q.w;
    }
    const float sz = np_sumsq64(zr);           // FROZEN tree
    float best = INFINITY; int bi = 0x7FFFFFFF;
#pragma unroll 1
    for (int r = 0; r < 8; ++r) {              // 8 codes/lane, SEQUENTIAL (no spill)
        const float4* e4 = reinterpret_cast<const float4*>(cb) +
                           ((size_t)(lane * 8 + r) << 4);
        float a = 0.f;
#pragma unroll
        for (int g = 0; g < 16; ++g) {         // FROZEN ascending-d chain
            float4 q = e4[g];
            a = fmaf(zr[4*g+0], q.x, a);
            a = fmaf(zr[4*g+1], q.y, a);
            a = fmaf(zr[4*g+2], q.z, a);
            a = fmaf(zr[4*g+3], q.w, a);
        }
        float s = __fadd_rn(__fsub_rn(sz, __fmul_rn(2.0f, a)),
                            norms[lane * 8 + r]);
        if (s < best) { best = s; bi = lane * 8 + r; }
    }
#pragma unroll
    for (int off = 1; off < 64; off <<= 1) {   // (value, index) first-min reduce
        float os = __shfl_xor(best, off, 64);
        int   ok = __shfl_xor(bi, off, 64);
        if (os < best || (os == best && ok < bi)) { best = os; bi = ok; }
    }
    if (lane == 0) out[pt] = bi;
}

__global__ __launch_bounds__(256)
void vq_cleanup_kernel(const float* __restrict__ z, const float* __restrict__ cb,
                       const float* __restrict__ norms,
                       const int* __restrict__ cnt, const int* __restrict__ list,
                       int cap, int* __restrict__ out, int n) {
    const int lane   = threadIdx.x & 63;
    const int wid    = (blockIdx.x * blockDim.x + threadIdx.x) >> 6;
    const int nwaves = (gridDim.x * blockDim.x) >> 6;

    int total = *cnt;
    int lim   = total < cap ? total : cap;
    for (int i = wid; i < lim; i += nwaves)
        vq_rescan_point(z, cb, norms, out, list[i], lane);

    if (total > cap) {   // overflow fallback: scan out[] for bit-31 flags
        for (int b = wid * 64; b < n; b += nwaves * 64) {
            int t = b + lane;
            int v = (t < n) ? out[t] : 0;
            unsigned long long m = __ballot(v < 0);
            while (m) {
                int bb = __ffsll(m) - 1;
                m &= m - 1ull;
                vq_rescan_point(z, cb, norms, out, b + bb, lane);
            }
        }
    }
}

extern "C" void kernel_launch(void* const* d_in, const int* in_sizes, int n_in,
                              void* d_out, int out_size, void* d_ws, size_t ws_size,
                              hipStream_t stream) {
    const float* z  = (const float*)d_in[0];
    const float* cb = (const float*)d_in[1];
    int n = in_sizes[0] / D_DIM;           // 131072 points
    float* norms = (float*)d_ws;
    int*   cnt   = (int*)((char*)d_ws + WS_CNT_OFF);
    int* out = (int*)d_out;

    bool fast = ws_size >= (size_t)WS_LIST_OFF + 4096;
    vq_prep_kernel<<<(K_CODES + 255) / 256, 256, 0, stream>>>(cb, norms, fast ? 1 : 0);

    if (fast) {
        const unsigned short* eh = (const unsigned short*)((char*)d_ws + WS_EH_OFF);
        const unsigned short* el = (const unsigned short*)((char*)d_ws + WS_EL_OFF);
        int* list = (int*)((char*)d_ws + WS_LIST_OFF);
        int  cap  = (int)((ws_size - WS_LIST_OFF) / 4);
        vq_pass1_stream<<<(n + BM - 1) / BM, THREADS, 0, stream>>>(
            z, eh, el, norms, out, cnt, list, cap, n);
        vq_cleanup_kernel<<<512, 256, 0, stream>>>(z, cb, norms, cnt, list, cap, out, n);
    } else {
        int* list = (int*)d_ws + 513;
        int  cap  = (int)(ws_size / 4) - 513; if (cap < 0) cap = 0;
        vq_pass1_legacy<<<(n + 127) / 128, THREADS, 0, stream>>>(
            z, cb, norms, out, cnt, list, cap, n);
        vq_cleanup_kernel<<<512, 256, 0, stream>>>(z, cb, norms, cnt, list, cap, out, n);
    }
}

// Round 18
// 61.002 us; speedup vs baseline: 1.2496x; 1.2375x over previous
//
#include <hip/hip_runtime.h>
#include <math.h>

#define K_CODES 512
#define D_DIM   64
#define BM      512        // points per block (8 waves x 4 pt-tiles)
#define THREADS 512
#define LSTR    72         // padded presplit row stride (ushorts); row = 144 B
#define EPS_GAP 4e-5f      // certified: 2*(dref~8e-6 + dacc~2e-6)=2e-5, 2x margin

// ws layout (bytes): [0,2048) norms | [2048) cnt | [4096,77824) eh presplit
// bf16 [512][72] | [77824,151552) el | [151552,..) worklist
#define WS_CNT_OFF  2048
#define WS_EH_OFF   4096
#define WS_EL_OFF   77824
#define WS_LIST_OFF 151552

typedef __attribute__((ext_vector_type(8))) short short8v;  // 8 bf16 (4 VGPRs)
typedef __attribute__((ext_vector_type(4))) float f32x4;

// ---------- FROZEN numerics (bit-exact vs np reference since R3) ----------
__device__ __forceinline__ float np_sumsq64(const float* zarr) {
    float L[16];
#pragma unroll
    for (int j = 0; j < 16; ++j)
        L[j] = __fadd_rn(
            __fadd_rn(__fmul_rn(zarr[j],      zarr[j]),
                      __fmul_rn(zarr[j + 16], zarr[j + 16])),
            __fadd_rn(__fmul_rn(zarr[j + 32], zarr[j + 32]),
                      __fmul_rn(zarr[j + 48], zarr[j + 48])));
    float m[8];
#pragma unroll
    for (int j = 0; j < 8; ++j) m[j] = __fadd_rn(L[j], L[j + 8]);
    float n4[4];
#pragma unroll
    for (int j = 0; j < 4; ++j) n4[j] = __fadd_rn(m[j], m[j + 4]);
    return __fadd_rn(__fadd_rn(n4[0], n4[2]), __fadd_rn(n4[1], n4[3]));
}

// ---------- bf16 split helpers (exact: x = hi + lo + r, |r| <= 2^-18|x|) ----------
__device__ __forceinline__ unsigned short f32_bf16_rne(float x) {
    unsigned int u = __float_as_uint(x);
    unsigned int r = (u + 0x7FFFu + ((u >> 16) & 1u)) >> 16;
    return (unsigned short)r;
}
__device__ __forceinline__ float bf16_f32(unsigned short h) {
    return __uint_as_float(((unsigned int)h) << 16);
}
__device__ __forceinline__ void split2(float x, unsigned short& h, unsigned short& l) {
    h = f32_bf16_rne(x);
    l = f32_bf16_rne(x - bf16_f32(h));   // x - hi is exact in fp32
}

// ---------- prep (4x parallel): norms + counter zero + presplit codebook ----------
// thread g: code k = g>>2, quarter q = g&3 handles elems [16q,16q+16);
// q==0 additionally computes the FROZEN norm; q==3 zeros the row pad.
__global__ __launch_bounds__(256)
void vq_prep_kernel(const float* __restrict__ cb, float* __restrict__ ws,
                    int do_split) {
    int g = blockIdx.x * blockDim.x + threadIdx.x;
    if (g == 0) *reinterpret_cast<int*>((char*)ws + WS_CNT_OFF) = 0;
    int k = g >> 2, q = g & 3;
    if (k >= K_CODES) return;
    const float* row = cb + (size_t)k * D_DIM;
    if (q == 0) {
        float e[D_DIM];
        const float4* p = reinterpret_cast<const float4*>(row);
#pragma unroll
        for (int i = 0; i < 16; ++i) {
            float4 v = p[i];
            e[4*i+0]=v.x; e[4*i+1]=v.y; e[4*i+2]=v.z; e[4*i+3]=v.w;
        }
        ws[k] = np_sumsq64(e);
    }
    if (do_split) {
        unsigned short* eh = reinterpret_cast<unsigned short*>((char*)ws + WS_EH_OFF)
                             + (size_t)k * LSTR;
        unsigned short* el = reinterpret_cast<unsigned short*>((char*)ws + WS_EL_OFF)
                             + (size_t)k * LSTR;
#pragma unroll
        for (int i = 16 * q; i < 16 * q + 16; ++i) {
            unsigned short h, l;
            split2(row[i], h, l);            // EXACT same split as always
            eh[i] = h; el[i] = l;
        }
        if (q == 3)
#pragma unroll
            for (int i = D_DIM; i < LSTR; ++i) { eh[i] = 0; el[i] = 0; }
    }
}

// ---------- Pass 1 MONO: whole presplit codebook in LDS, ZERO main-loop barriers ----------
// R14-R17 evidence: every per-chunk-barrier variant sits at 40-44us vs ~15us
// of pipe work — the barrier's vmcnt/lgkm drain cadence is the ceiling (m97
// lesson); the barrier-free L2-stream variant (R17) lost to scattered-load
// latency instead. This kernel keeps LDS staging AND deletes all main-loop
// barriers: 144 KiB presplit + 2 KiB norms = 149.5 KiB fits the 160 KiB LDS.
// 1 block/CU (512 thr, 8 waves); allocator sees 2 waves/SIMD max -> 256-VGPR
// budget -> no spill pressure. 32-ct loop is pure {ds_read,MFMA,epilogue},
// fully software-pipelineable. MFMA inputs bit-identical to R11+.
__global__ __launch_bounds__(512)
void vq_pass1_mono(const float* __restrict__ z,
                   const unsigned short* __restrict__ eh_g,
                   const unsigned short* __restrict__ el_g,
                   const float* __restrict__ norms, int* __restrict__ out,
                   int* __restrict__ cnt, int* __restrict__ list, int cap, int n) {
    __shared__ __align__(16) unsigned short ehS[K_CODES * LSTR];  // 72 KiB
    __shared__ __align__(16) unsigned short elS[K_CODES * LSTR];  // 72 KiB
    __shared__ __align__(16) float nrmS[K_CODES];                 // 2 KiB

    const int tid  = threadIdx.x;
    const int l    = tid & 63;
    const int w    = tid >> 6;        // wave 0..7 -> pt-tiles {4w..4w+3}
    const int j    = l >> 4;          // k-chunk / C-row-group selector 0..3
    const int c16  = l & 15;
    const int base = blockIdx.x * BM;

    // ---- stage ENTIRE presplit codebook once: 9x16B per thread per array ----
    {
        const char* esrc = (const char*)eh_g;
        const char* lsrc = (const char*)el_g;
#pragma unroll
        for (int r = 0; r < 9; ++r) {
            size_t off = ((size_t)tid + (size_t)r * THREADS) * 16;   // 73728 B
            __builtin_amdgcn_global_load_lds(
                (const __attribute__((address_space(1))) void*)(esrc + off),
                (__attribute__((address_space(3))) void*)((char*)ehS + off), 16, 0, 0);
            __builtin_amdgcn_global_load_lds(
                (const __attribute__((address_space(1))) void*)(lsrc + off),
                (__attribute__((address_space(3))) void*)((char*)elS + off), 16, 0, 0);
        }
        if (tid < K_CODES / 4)
            reinterpret_cast<float4*>(nrmS)[tid] =
                reinterpret_cast<const float4*>(norms)[tid];
    }

    // ---- z B-fragments direct from global, split in-register (overlaps DMA) ----
    short8v bzh[4][2], bzl[4][2];
#pragma unroll
    for (int p = 0; p < 4; ++p) {
        int row = base + (4 * w + p) * 16 + c16;
        if (row >= n) row = n - 1;
        const float* zp = z + (size_t)row * D_DIM + j * 8;
#pragma unroll
        for (int h = 0; h < 2; ++h) {
            float4 v0 = *reinterpret_cast<const float4*>(zp + h * 32);
            float4 v1 = *reinterpret_cast<const float4*>(zp + h * 32 + 4);
            unsigned short hh[8], ll[8];
            split2(v0.x, hh[0], ll[0]); split2(v0.y, hh[1], ll[1]);
            split2(v0.z, hh[2], ll[2]); split2(v0.w, hh[3], ll[3]);
            split2(v1.x, hh[4], ll[4]); split2(v1.y, hh[5], ll[5]);
            split2(v1.z, hh[6], ll[6]); split2(v1.w, hh[7], ll[7]);
            short8v th, tl;
#pragma unroll
            for (int i = 0; i < 8; ++i) { th[i] = (short)hh[i]; tl[i] = (short)ll[i]; }
            bzh[p][h] = th; bzl[p][h] = tl;
        }
    }

    __syncthreads();   // ONE barrier: staging DMA drained; none after this

    float m1[4] = {INFINITY, INFINITY, INFINITY, INFINITY};
    float m2[4] = {INFINITY, INFINITY, INFINITY, INFINITY};
    int   i1[4] = {0, 0, 0, 0};

#pragma unroll 4
    for (int ct = 0; ct < 32; ++ct) {
        int ar = (ct * 16 + c16) * LSTR + j * 8;
        short8v aeh0 = *reinterpret_cast<const short8v*>(&ehS[ar]);
        short8v aeh1 = *reinterpret_cast<const short8v*>(&ehS[ar + 32]);
        short8v ael0 = *reinterpret_cast<const short8v*>(&elS[ar]);
        short8v ael1 = *reinterpret_cast<const short8v*>(&elS[ar + 32]);
        float4 nr = *reinterpret_cast<const float4*>(&nrmS[ct * 16 + j * 4]);
        float nra[4] = {nr.x, nr.y, nr.z, nr.w};
        int kg0 = ct * 16 + j * 4;
#pragma unroll
        for (int p = 0; p < 4; ++p) {
            f32x4 acc = {0.f, 0.f, 0.f, 0.f};
            acc = __builtin_amdgcn_mfma_f32_16x16x32_bf16(aeh0, bzh[p][0], acc, 0, 0, 0);
            acc = __builtin_amdgcn_mfma_f32_16x16x32_bf16(aeh1, bzh[p][1], acc, 0, 0, 0);
            acc = __builtin_amdgcn_mfma_f32_16x16x32_bf16(aeh0, bzl[p][0], acc, 0, 0, 0);
            acc = __builtin_amdgcn_mfma_f32_16x16x32_bf16(aeh1, bzl[p][1], acc, 0, 0, 0);
            acc = __builtin_amdgcn_mfma_f32_16x16x32_bf16(ael0, bzh[p][0], acc, 0, 0, 0);
            acc = __builtin_amdgcn_mfma_f32_16x16x32_bf16(ael1, bzh[p][1], acc, 0, 0, 0);
#pragma unroll
            for (int r = 0; r < 4; ++r) {
                float s = fmaf(-2.0f, acc[r], nra[r]);   // accuracy-only path
                int kg = kg0 + r;
                bool lt1 = s < m1[p];
                float nm2 = lt1 ? m1[p] : fminf(s, m2[p]);
                i1[p] = lt1 ? kg : i1[p];
                m1[p] = lt1 ? s : m1[p];
                m2[p] = nm2;
            }
        }
    }

    // ---- butterfly merge (pure shfl) + compacting store ----
#pragma unroll
    for (int p = 0; p < 4; ++p) {
        float a1 = m1[p], a2 = m2[p]; int ai = i1[p];
#pragma unroll
        for (int off = 16; off <= 32; off <<= 1) {
            float o1 = __shfl_xor(a1, off, 64);
            float o2 = __shfl_xor(a2, off, 64);
            int   oi = __shfl_xor(ai, off, 64);
            float hi = fmaxf(a1, o1);
            bool take = o1 < a1;                 // ties keep own (tie => flagged anyway)
            ai = take ? oi : ai;
            a1 = take ? o1 : a1;
            a2 = fminf(hi, fminf(a2, o2));
        }
        int  ptg    = base + (4 * w + p) * 16 + c16;
        bool writer = (j == 0) && (ptg < n);
        bool flag   = writer && (a2 - a1 <= EPS_GAP);
        unsigned long long m = __ballot(flag);
        int abase = 0;
        if (m) {
            int leader = __ffsll(m) - 1;
            if (l == leader) abase = atomicAdd(cnt, __popcll(m));
            abase = __shfl(abase, leader, 64);
        }
        if (writer) {
            int val = ai;
            if (flag) {
                int rank = __popcll(m & ((1ull << l) - 1ull));
                int slot = abase + rank;
                if (slot < cap) list[slot] = ptg;       // worklist path
                else            val |= (int)0x80000000; // overflow fallback
            }
            out[ptg] = val;
        }
    }
}

// ---------- Pass 1 LEGACY (R13 verbatim, BM=128): used only if ws too small ----------
__global__ __launch_bounds__(256)
void vq_pass1_legacy(const float* __restrict__ z, const float* __restrict__ cb,
                     const float* __restrict__ norms, int* __restrict__ out,
                     int* __restrict__ cnt, int* __restrict__ list, int cap, int n) {
    __shared__ unsigned short zhS[128 * LSTR];
    __shared__ unsigned short zlS[128 * LSTR];
    __shared__ unsigned short ehS[128 * LSTR];
    __shared__ unsigned short elS[128 * LSTR];
    __shared__ float nrmL[128];

    const int tid  = threadIdx.x;
    const int l    = tid & 63;
    const int w    = tid >> 6;
    const int j    = l >> 4;
    const int c16  = l & 15;
    const int base = blockIdx.x * 128;

    const float4* z4 = reinterpret_cast<const float4*>(z);
#pragma unroll
    for (int rep = 0; rep < 8; ++rep) {
        int flat = rep * 256 + tid;
        int pt   = flat >> 4;
        int dblk = flat & 15;
        int gp = base + pt; if (gp >= n) gp = n - 1;
        float4 v = z4[(size_t)gp * 16 + dblk];
        ushort4 h, lo;
        split2(v.x, h.x, lo.x); split2(v.y, h.y, lo.y);
        split2(v.z, h.z, lo.z); split2(v.w, h.w, lo.w);
        *reinterpret_cast<ushort4*>(&zhS[pt * LSTR + dblk * 4]) = h;
        *reinterpret_cast<ushort4*>(&zlS[pt * LSTR + dblk * 4]) = lo;
    }
    __syncthreads();

    short8v bzh[2][2], bzl[2][2];
#pragma unroll
    for (int p = 0; p < 2; ++p) {
        int pr = ((2 * w + p) * 16 + c16) * LSTR;
#pragma unroll
        for (int h = 0; h < 2; ++h) {
            int off = pr + h * 32 + j * 8;
            bzh[p][h] = *reinterpret_cast<const short8v*>(&zhS[off]);
            bzl[p][h] = *reinterpret_cast<const short8v*>(&zlS[off]);
        }
    }

    float m1[2] = {INFINITY, INFINITY};
    float m2[2] = {INFINITY, INFINITY};
    int   i1[2] = {0, 0};

    for (int c = 0; c < 4; ++c) {
        __syncthreads();
        const float4* cb4 = reinterpret_cast<const float4*>(cb);
#pragma unroll
        for (int rep = 0; rep < 8; ++rep) {
            int flat = rep * 256 + tid;
            int code = flat >> 4;
            int dblk = flat & 15;
            float4 v = cb4[(size_t)(c * 128 + code) * 16 + dblk];
            ushort4 h, lo;
            split2(v.x, h.x, lo.x); split2(v.y, h.y, lo.y);
            split2(v.z, h.z, lo.z); split2(v.w, h.w, lo.w);
            *reinterpret_cast<ushort4*>(&ehS[code * LSTR + dblk * 4]) = h;
            *reinterpret_cast<ushort4*>(&elS[code * LSTR + dblk * 4]) = lo;
        }
        if (tid < 32)
            reinterpret_cast<float4*>(nrmL)[tid] =
                reinterpret_cast<const float4*>(norms)[c * 32 + tid];
        __syncthreads();

#pragma unroll
        for (int ct = 0; ct < 8; ++ct) {
            int ar = (ct * 16 + c16) * LSTR + j * 8;
            short8v aeh0 = *reinterpret_cast<const short8v*>(&ehS[ar]);
            short8v aeh1 = *reinterpret_cast<const short8v*>(&ehS[ar + 32]);
            short8v ael0 = *reinterpret_cast<const short8v*>(&elS[ar]);
            short8v ael1 = *reinterpret_cast<const short8v*>(&elS[ar + 32]);
            float4 nr = *reinterpret_cast<const float4*>(&nrmL[ct * 16 + j * 4]);
            float nra[4] = {nr.x, nr.y, nr.z, nr.w};
            int kg0 = c * 128 + ct * 16 + j * 4;
#pragma unroll
            for (int p = 0; p < 2; ++p) {
                f32x4 acc = {0.f, 0.f, 0.f, 0.f};
                acc = __builtin_amdgcn_mfma_f32_16x16x32_bf16(aeh0, bzh[p][0], acc, 0, 0, 0);
                acc = __builtin_amdgcn_mfma_f32_16x16x32_bf16(aeh1, bzh[p][1], acc, 0, 0, 0);
                acc = __builtin_amdgcn_mfma_f32_16x16x32_bf16(aeh0, bzl[p][0], acc, 0, 0, 0);
                acc = __builtin_amdgcn_mfma_f32_16x16x32_bf16(aeh1, bzl[p][1], acc, 0, 0, 0);
                acc = __builtin_amdgcn_mfma_f32_16x16x32_bf16(ael0, bzh[p][0], acc, 0, 0, 0);
                acc = __builtin_amdgcn_mfma_f32_16x16x32_bf16(ael1, bzh[p][1], acc, 0, 0, 0);
#pragma unroll
                for (int r = 0; r < 4; ++r) {
                    float s = fmaf(-2.0f, acc[r], nra[r]);
                    int kg = kg0 + r;
                    bool lt1 = s < m1[p];
                    float nm2 = lt1 ? m1[p] : fminf(s, m2[p]);
                    i1[p] = lt1 ? kg : i1[p];
                    m1[p] = lt1 ? s : m1[p];
                    m2[p] = nm2;
                }
            }
        }
    }

#pragma unroll
    for (int p = 0; p < 2; ++p) {
        float a1 = m1[p], a2 = m2[p]; int ai = i1[p];
#pragma unroll
        for (int off = 16; off <= 32; off <<= 1) {
            float o1 = __shfl_xor(a1, off, 64);
            float o2 = __shfl_xor(a2, off, 64);
            int   oi = __shfl_xor(ai, off, 64);
            float hi = fmaxf(a1, o1);
            bool take = o1 < a1;
            ai = take ? oi : ai;
            a1 = take ? o1 : a1;
            a2 = fminf(hi, fminf(a2, o2));
        }
        int  ptg    = base + (2 * w + p) * 16 + c16;
        bool writer = (j == 0) && (ptg < n);
        bool flag   = writer && (a2 - a1 <= EPS_GAP);
        unsigned long long m = __ballot(flag);
        int abase = 0;
        if (m) {
            int leader = __ffsll(m) - 1;
            if (l == leader) abase = atomicAdd(cnt, __popcll(m));
            abase = __shfl(abase, leader, 64);
        }
        if (writer) {
            int val = ai;
            if (flag) {
                int rank = __popcll(m & ((1ull << l) - 1ull));
                int slot = abase + rank;
                if (slot < cap) list[slot] = ptg;
                else            val |= (int)0x80000000;
            }
            out[ptg] = val;
        }
    }
}

// ---------- Pass 2: one BLOCK (4 waves, 2 codes/lane) per flagged point ----------
// R12-R14 cleanup was wave-per-point (~7us/pt L2-latency-bound, ~10us tail).
// Block-per-point gives 4x parallel codes per point; 2048 blocks cover the
// ~2500-flag worklist in 1-2 rounds. FROZEN chain; (val,idx) lexicographic
// reduce == global ascending-k first-min.
__global__ __launch_bounds__(256)
void vq_cleanup_kernel(const float* __restrict__ z, const float* __restrict__ cb,
                       const float* __restrict__ norms,
                       const int* __restrict__ cnt, const int* __restrict__ list,
                       int cap, int* __restrict__ out, int n) {
    __shared__ float rbv[4];
    __shared__ int   rbi[4];
    const int tid  = threadIdx.x;
    const int lane = tid & 63;
    const int wv   = tid >> 6;

    int total = *cnt;
    int lim   = total < cap ? total : cap;

    for (int i = blockIdx.x; i < lim; i += gridDim.x) {
        int pt = list[i];
        float zr[D_DIM];
        const float4* zp = reinterpret_cast<const float4*>(z + (size_t)pt * D_DIM);
#pragma unroll
        for (int g = 0; g < 16; ++g) {
            float4 q = zp[g];
            zr[4*g+0]=q.x; zr[4*g+1]=q.y; zr[4*g+2]=q.z; zr[4*g+3]=q.w;
        }
        const float sz = np_sumsq64(zr);           // FROZEN tree
        float best = INFINITY; int bi = 0x7FFFFFFF;
#pragma unroll 1
        for (int r = 0; r < 2; ++r) {              // 2 codes/thread, sequential
            int k = tid * 2 + r;
            const float4* e4 = reinterpret_cast<const float4*>(cb) + ((size_t)k << 4);
            float a = 0.f;
#pragma unroll
            for (int g = 0; g < 16; ++g) {         // FROZEN ascending-d chain
                float4 q = e4[g];
                a = fmaf(zr[4*g+0], q.x, a);
                a = fmaf(zr[4*g+1], q.y, a);
                a = fmaf(zr[4*g+2], q.z, a);
                a = fmaf(zr[4*g+3], q.w, a);
            }
            float s = __fadd_rn(__fsub_rn(sz, __fmul_rn(2.0f, a)), norms[k]);
            if (s < best || (s == best && k < bi)) { best = s; bi = k; }
        }
#pragma unroll
        for (int off = 1; off < 64; off <<= 1) {   // wave (value,index) reduce
            float os = __shfl_xor(best, off, 64);
            int   ok = __shfl_xor(bi, off, 64);
            if (os < best || (os == best && ok < bi)) { best = os; bi = ok; }
        }
        if (lane == 0) { rbv[wv] = best; rbi[wv] = bi; }
        __syncthreads();
        if (tid == 0) {
            float b = rbv[0]; int id = rbi[0];
#pragma unroll
            for (int q = 1; q < 4; ++q) {
                float v = rbv[q]; int vi = rbi[q];
                if (v < b || (v == b && vi < id)) { b = v; id = vi; }
            }
            out[pt] = id;
        }
        __syncthreads();
    }

    // overflow fallback: wave-per-point scan of out[] for bit-31 flags
    if (total > cap) {
        const int wid    = (blockIdx.x * blockDim.x + tid) >> 6;
        const int nwaves = (gridDim.x * blockDim.x) >> 6;
        for (int b = wid * 64; b < n; b += nwaves * 64) {
            int t = b + lane;
            int v = (t < n) ? out[t] : 0;
            unsigned long long m = __ballot(v < 0);
            while (m) {
                int bb = __ffsll(m) - 1;
                m &= m - 1ull;
                int pt = b + bb;
                float zr[D_DIM];
                const float4* zp = reinterpret_cast<const float4*>(z + (size_t)pt * D_DIM);
#pragma unroll
                for (int g = 0; g < 16; ++g) {
                    float4 q = zp[g];
                    zr[4*g+0]=q.x; zr[4*g+1]=q.y; zr[4*g+2]=q.z; zr[4*g+3]=q.w;
                }
                const float sz = np_sumsq64(zr);
                float best = INFINITY; int bi = 0x7FFFFFFF;
#pragma unroll 1
                for (int r = 0; r < 8; ++r) {
                    const float4* e4 = reinterpret_cast<const float4*>(cb) +
                                       ((size_t)(lane * 8 + r) << 4);
                    float a = 0.f;
#pragma unroll
                    for (int g = 0; g < 16; ++g) {
                        float4 q = e4[g];
                        a = fmaf(zr[4*g+0], q.x, a);
                        a = fmaf(zr[4*g+1], q.y, a);
                        a = fmaf(zr[4*g+2], q.z, a);
                        a = fmaf(zr[4*g+3], q.w, a);
                    }
                    float s = __fadd_rn(__fsub_rn(sz, __fmul_rn(2.0f, a)),
                                        norms[lane * 8 + r]);
                    if (s < best) { best = s; bi = lane * 8 + r; }
                }
#pragma unroll
                for (int off = 1; off < 64; off <<= 1) {
                    float os = __shfl_xor(best, off, 64);
                    int   ok = __shfl_xor(bi, off, 64);
                    if (os < best || (os == best && ok < bi)) { best = os; bi = ok; }
                }
                if (lane == 0) out[pt] = bi;
            }
        }
    }
}

extern "C" void kernel_launch(void* const* d_in, const int* in_sizes, int n_in,
                              void* d_out, int out_size, void* d_ws, size_t ws_size,
                              hipStream_t stream) {
    const float* z  = (const float*)d_in[0];
    const float* cb = (const float*)d_in[1];
    int n = in_sizes[0] / D_DIM;           // 131072 points
    float* norms = (float*)d_ws;
    int*   cnt   = (int*)((char*)d_ws + WS_CNT_OFF);
    int* out = (int*)d_out;

    bool fast = ws_size >= (size_t)WS_LIST_OFF + 4096;
    vq_prep_kernel<<<(4 * K_CODES + 255) / 256, 256, 0, stream>>>(cb, norms, fast ? 1 : 0);

    if (fast) {
        const unsigned short* eh = (const unsigned short*)((char*)d_ws + WS_EH_OFF);
        const unsigned short* el = (const unsigned short*)((char*)d_ws + WS_EL_OFF);
        int* list = (int*)((char*)d_ws + WS_LIST_OFF);
        int  cap  = (int)((ws_size - WS_LIST_OFF) / 4);
        vq_pass1_mono<<<(n + BM - 1) / BM, THREADS, 0, stream>>>(
            z, eh, el, norms, out, cnt, list, cap, n);
        vq_cleanup_kernel<<<2048, 256, 0, stream>>>(z, cb, norms, cnt, list, cap, out, n);
    } else {
        int* list = (int*)d_ws + 513;
        int  cap  = (int)(ws_size / 4) - 513; if (cap < 0) cap = 0;
        vq_pass1_legacy<<<(n + 127) / 128, 256, 0, stream>>>(
            z, cb, norms, out, cnt, list, cap, n);
        vq_cleanup_kernel<<<2048, 256, 0, stream>>>(z, cb, norms, cnt, list, cap, out, n);
    }
}

// Round 19
// 60.697 us; speedup vs baseline: 1.2558x; 1.0050x over previous
//
#include <hip/hip_runtime.h>
#include <math.h>

#define K_CODES 512
#define D_DIM   64
#define BM      512        // points per block (8 waves x 4 pt-tiles)
#define THREADS 512
#define LSTR    72         // padded presplit row stride (ushorts); row = 144 B
#define EPS_GAP 4e-5f      // certified: 2*(dref~8e-6 + dacc~2e-6)=2e-5, 2x margin

// ws layout (bytes): [0,2048) norms | [2048) cnt | [4096,77824) eh presplit
// bf16 [512][72] | [77824,151552) el | [151552,..) worklist
#define WS_CNT_OFF  2048
#define WS_EH_OFF   4096
#define WS_EL_OFF   77824
#define WS_LIST_OFF 151552

typedef __attribute__((ext_vector_type(8))) short short8v;  // 8 bf16 (4 VGPRs)
typedef __attribute__((ext_vector_type(4))) float f32x4;

// ---------- FROZEN numerics (bit-exact vs np reference since R3) ----------
__device__ __forceinline__ float np_sumsq64(const float* zarr) {
    float L[16];
#pragma unroll
    for (int j = 0; j < 16; ++j)
        L[j] = __fadd_rn(
            __fadd_rn(__fmul_rn(zarr[j],      zarr[j]),
                      __fmul_rn(zarr[j + 16], zarr[j + 16])),
            __fadd_rn(__fmul_rn(zarr[j + 32], zarr[j + 32]),
                      __fmul_rn(zarr[j + 48], zarr[j + 48])));
    float m[8];
#pragma unroll
    for (int j = 0; j < 8; ++j) m[j] = __fadd_rn(L[j], L[j + 8]);
    float n4[4];
#pragma unroll
    for (int j = 0; j < 4; ++j) n4[j] = __fadd_rn(m[j], m[j + 4]);
    return __fadd_rn(__fadd_rn(n4[0], n4[2]), __fadd_rn(n4[1], n4[3]));
}

// ---------- bf16 split helpers (exact: x = hi + lo + r, |r| <= 2^-18|x|) ----------
__device__ __forceinline__ unsigned short f32_bf16_rne(float x) {
    unsigned int u = __float_as_uint(x);
    unsigned int r = (u + 0x7FFFu + ((u >> 16) & 1u)) >> 16;
    return (unsigned short)r;
}
__device__ __forceinline__ float bf16_f32(unsigned short h) {
    return __uint_as_float(((unsigned int)h) << 16);
}
__device__ __forceinline__ void split2(float x, unsigned short& h, unsigned short& l) {
    h = f32_bf16_rne(x);
    l = f32_bf16_rne(x - bf16_f32(h));   // x - hi is exact in fp32
}

// ---------- prep (4x parallel): norms + counter zero + presplit codebook ----------
__global__ __launch_bounds__(256)
void vq_prep_kernel(const float* __restrict__ cb, float* __restrict__ ws,
                    int do_split) {
    int g = blockIdx.x * blockDim.x + threadIdx.x;
    if (g == 0) *reinterpret_cast<int*>((char*)ws + WS_CNT_OFF) = 0;
    int k = g >> 2, q = g & 3;
    if (k >= K_CODES) return;
    const float* row = cb + (size_t)k * D_DIM;
    if (q == 0) {
        float e[D_DIM];
        const float4* p = reinterpret_cast<const float4*>(row);
#pragma unroll
        for (int i = 0; i < 16; ++i) {
            float4 v = p[i];
            e[4*i+0]=v.x; e[4*i+1]=v.y; e[4*i+2]=v.z; e[4*i+3]=v.w;
        }
        ws[k] = np_sumsq64(e);
    }
    if (do_split) {
        unsigned short* eh = reinterpret_cast<unsigned short*>((char*)ws + WS_EH_OFF)
                             + (size_t)k * LSTR;
        unsigned short* el = reinterpret_cast<unsigned short*>((char*)ws + WS_EL_OFF)
                             + (size_t)k * LSTR;
#pragma unroll
        for (int i = 16 * q; i < 16 * q + 16; ++i) {
            unsigned short h, l;
            split2(row[i], h, l);            // EXACT same split as always
            eh[i] = h; el[i] = l;
        }
        if (q == 3)
#pragma unroll
            for (int i = D_DIM; i < LSTR; ++i) { eh[i] = 0; el[i] = 0; }
    }
}

// ---------- Pass 1 MONO+STAGGER: whole codebook in LDS, waves desynchronized ----------
// R18 recount: per-SIMD MFMA throughput is ~19.4 cyc per 16x16x32 (2075 TF
// = 4.85 cyc/CU across 4 SIMDs), so 2 waves x 768 MFMA = 12.4us of matrix-
// pipe floor; observed 40us at MfmaUtil 22% = lockstep waves idling the pipe
// during their identical ~210-cyc epilogues. Fix: each wave starts its ct
// sweep at tile 4*w (codebook fully LDS-resident -> any visit order valid).
// (m1,m2) = (min, 2nd-min) of a value SET: order-independent; i1 differs only
// on exact ties (gap 0 <= EPS -> flagged -> cleanup). T5 setprio around the
// MFMA cluster now has wave-role diversity to arbitrate (m218b mechanism).
__global__ __launch_bounds__(512)
void vq_pass1_mono(const float* __restrict__ z,
                   const unsigned short* __restrict__ eh_g,
                   const unsigned short* __restrict__ el_g,
                   const float* __restrict__ norms, int* __restrict__ out,
                   int* __restrict__ cnt, int* __restrict__ list, int cap, int n) {
    __shared__ __align__(16) unsigned short ehS[K_CODES * LSTR];  // 72 KiB
    __shared__ __align__(16) unsigned short elS[K_CODES * LSTR];  // 72 KiB
    __shared__ __align__(16) float nrmS[K_CODES];                 // 2 KiB

    const int tid  = threadIdx.x;
    const int l    = tid & 63;
    const int w    = tid >> 6;        // wave 0..7 -> pt-tiles {4w..4w+3}
    const int j    = l >> 4;          // k-chunk / C-row-group selector 0..3
    const int c16  = l & 15;
    const int base = blockIdx.x * BM;

    // ---- stage ENTIRE presplit codebook once: 9x16B per thread per array ----
    {
        const char* esrc = (const char*)eh_g;
        const char* lsrc = (const char*)el_g;
#pragma unroll
        for (int r = 0; r < 9; ++r) {
            size_t off = ((size_t)tid + (size_t)r * THREADS) * 16;   // 73728 B
            __builtin_amdgcn_global_load_lds(
                (const __attribute__((address_space(1))) void*)(esrc + off),
                (__attribute__((address_space(3))) void*)((char*)ehS + off), 16, 0, 0);
            __builtin_amdgcn_global_load_lds(
                (const __attribute__((address_space(1))) void*)(lsrc + off),
                (__attribute__((address_space(3))) void*)((char*)elS + off), 16, 0, 0);
        }
        if (tid < K_CODES / 4)
            reinterpret_cast<float4*>(nrmS)[tid] =
                reinterpret_cast<const float4*>(norms)[tid];
    }

    // ---- z B-fragments direct from global, split in-register (overlaps DMA) ----
    short8v bzh[4][2], bzl[4][2];
#pragma unroll
    for (int p = 0; p < 4; ++p) {
        int row = base + (4 * w + p) * 16 + c16;
        if (row >= n) row = n - 1;
        const float* zp = z + (size_t)row * D_DIM + j * 8;
#pragma unroll
        for (int h = 0; h < 2; ++h) {
            float4 v0 = *reinterpret_cast<const float4*>(zp + h * 32);
            float4 v1 = *reinterpret_cast<const float4*>(zp + h * 32 + 4);
            unsigned short hh[8], ll[8];
            split2(v0.x, hh[0], ll[0]); split2(v0.y, hh[1], ll[1]);
            split2(v0.z, hh[2], ll[2]); split2(v0.w, hh[3], ll[3]);
            split2(v1.x, hh[4], ll[4]); split2(v1.y, hh[5], ll[5]);
            split2(v1.z, hh[6], ll[6]); split2(v1.w, hh[7], ll[7]);
            short8v th, tl;
#pragma unroll
            for (int i = 0; i < 8; ++i) { th[i] = (short)hh[i]; tl[i] = (short)ll[i]; }
            bzh[p][h] = th; bzl[p][h] = tl;
        }
    }

    __syncthreads();   // ONE barrier: staging DMA drained; none after this

    float m1[4] = {INFINITY, INFINITY, INFINITY, INFINITY};
    float m2[4] = {INFINITY, INFINITY, INFINITY, INFINITY};
    int   i1[4] = {0, 0, 0, 0};

#pragma unroll 4
    for (int cti = 0; cti < 32; ++cti) {
        const int ct = (cti + 4 * w) & 31;    // per-wave rotation (wave-uniform)
        int ar = (ct * 16 + c16) * LSTR + j * 8;
        short8v aeh0 = *reinterpret_cast<const short8v*>(&ehS[ar]);
        short8v aeh1 = *reinterpret_cast<const short8v*>(&ehS[ar + 32]);
        short8v ael0 = *reinterpret_cast<const short8v*>(&elS[ar]);
        short8v ael1 = *reinterpret_cast<const short8v*>(&elS[ar + 32]);
        float4 nr = *reinterpret_cast<const float4*>(&nrmS[ct * 16 + j * 4]);
        float nra[4] = {nr.x, nr.y, nr.z, nr.w};
        int kg0 = ct * 16 + j * 4;

        f32x4 acc0 = {0.f,0.f,0.f,0.f}, acc1 = {0.f,0.f,0.f,0.f};
        f32x4 acc2 = {0.f,0.f,0.f,0.f}, acc3 = {0.f,0.f,0.f,0.f};
        __builtin_amdgcn_s_setprio(1);
        acc0 = __builtin_amdgcn_mfma_f32_16x16x32_bf16(aeh0, bzh[0][0], acc0, 0, 0, 0);
        acc1 = __builtin_amdgcn_mfma_f32_16x16x32_bf16(aeh0, bzh[1][0], acc1, 0, 0, 0);
        acc2 = __builtin_amdgcn_mfma_f32_16x16x32_bf16(aeh0, bzh[2][0], acc2, 0, 0, 0);
        acc3 = __builtin_amdgcn_mfma_f32_16x16x32_bf16(aeh0, bzh[3][0], acc3, 0, 0, 0);
        acc0 = __builtin_amdgcn_mfma_f32_16x16x32_bf16(aeh1, bzh[0][1], acc0, 0, 0, 0);
        acc1 = __builtin_amdgcn_mfma_f32_16x16x32_bf16(aeh1, bzh[1][1], acc1, 0, 0, 0);
        acc2 = __builtin_amdgcn_mfma_f32_16x16x32_bf16(aeh1, bzh[2][1], acc2, 0, 0, 0);
        acc3 = __builtin_amdgcn_mfma_f32_16x16x32_bf16(aeh1, bzh[3][1], acc3, 0, 0, 0);
        acc0 = __builtin_amdgcn_mfma_f32_16x16x32_bf16(aeh0, bzl[0][0], acc0, 0, 0, 0);
        acc1 = __builtin_amdgcn_mfma_f32_16x16x32_bf16(aeh0, bzl[1][0], acc1, 0, 0, 0);
        acc2 = __builtin_amdgcn_mfma_f32_16x16x32_bf16(aeh0, bzl[2][0], acc2, 0, 0, 0);
        acc3 = __builtin_amdgcn_mfma_f32_16x16x32_bf16(aeh0, bzl[3][0], acc3, 0, 0, 0);
        acc0 = __builtin_amdgcn_mfma_f32_16x16x32_bf16(aeh1, bzl[0][1], acc0, 0, 0, 0);
        acc1 = __builtin_amdgcn_mfma_f32_16x16x32_bf16(aeh1, bzl[1][1], acc1, 0, 0, 0);
        acc2 = __builtin_amdgcn_mfma_f32_16x16x32_bf16(aeh1, bzl[2][1], acc2, 0, 0, 0);
        acc3 = __builtin_amdgcn_mfma_f32_16x16x32_bf16(aeh1, bzl[3][1], acc3, 0, 0, 0);
        acc0 = __builtin_amdgcn_mfma_f32_16x16x32_bf16(ael0, bzh[0][0], acc0, 0, 0, 0);
        acc1 = __builtin_amdgcn_mfma_f32_16x16x32_bf16(ael0, bzh[1][0], acc1, 0, 0, 0);
        acc2 = __builtin_amdgcn_mfma_f32_16x16x32_bf16(ael0, bzh[2][0], acc2, 0, 0, 0);
        acc3 = __builtin_amdgcn_mfma_f32_16x16x32_bf16(ael0, bzh[3][0], acc3, 0, 0, 0);
        acc0 = __builtin_amdgcn_mfma_f32_16x16x32_bf16(ael1, bzh[0][1], acc0, 0, 0, 0);
        acc1 = __builtin_amdgcn_mfma_f32_16x16x32_bf16(ael1, bzh[1][1], acc1, 0, 0, 0);
        acc2 = __builtin_amdgcn_mfma_f32_16x16x32_bf16(ael1, bzh[2][1], acc2, 0, 0, 0);
        acc3 = __builtin_amdgcn_mfma_f32_16x16x32_bf16(ael1, bzh[3][1], acc3, 0, 0, 0);
        __builtin_amdgcn_s_setprio(0);

        f32x4 accs[4] = {acc0, acc1, acc2, acc3};
#pragma unroll
        for (int p = 0; p < 4; ++p) {
#pragma unroll
            for (int r = 0; r < 4; ++r) {
                float s = fmaf(-2.0f, accs[p][r], nra[r]);   // accuracy-only path
                int kg = kg0 + r;
                bool lt1 = s < m1[p];
                float nm2 = lt1 ? m1[p] : fminf(s, m2[p]);
                i1[p] = lt1 ? kg : i1[p];
                m1[p] = lt1 ? s : m1[p];
                m2[p] = nm2;
            }
        }
    }

    // ---- butterfly merge (pure shfl) + compacting store ----
#pragma unroll
    for (int p = 0; p < 4; ++p) {
        float a1 = m1[p], a2 = m2[p]; int ai = i1[p];
#pragma unroll
        for (int off = 16; off <= 32; off <<= 1) {
            float o1 = __shfl_xor(a1, off, 64);
            float o2 = __shfl_xor(a2, off, 64);
            int   oi = __shfl_xor(ai, off, 64);
            float hi = fmaxf(a1, o1);
            bool take = o1 < a1;                 // ties keep own (tie => flagged anyway)
            ai = take ? oi : ai;
            a1 = take ? o1 : a1;
            a2 = fminf(hi, fminf(a2, o2));
        }
        int  ptg    = base + (4 * w + p) * 16 + c16;
        bool writer = (j == 0) && (ptg < n);
        bool flag   = writer && (a2 - a1 <= EPS_GAP);
        unsigned long long m = __ballot(flag);
        int abase = 0;
        if (m) {
            int leader = __ffsll(m) - 1;
            if (l == leader) abase = atomicAdd(cnt, __popcll(m));
            abase = __shfl(abase, leader, 64);
        }
        if (writer) {
            int val = ai;
            if (flag) {
                int rank = __popcll(m & ((1ull << l) - 1ull));
                int slot = abase + rank;
                if (slot < cap) list[slot] = ptg;       // worklist path
                else            val |= (int)0x80000000; // overflow fallback
            }
            out[ptg] = val;
        }
    }
}

// ---------- Pass 1 LEGACY (R13 verbatim, BM=128): used only if ws too small ----------
__global__ __launch_bounds__(256)
void vq_pass1_legacy(const float* __restrict__ z, const float* __restrict__ cb,
                     const float* __restrict__ norms, int* __restrict__ out,
                     int* __restrict__ cnt, int* __restrict__ list, int cap, int n) {
    __shared__ unsigned short zhS[128 * LSTR];
    __shared__ unsigned short zlS[128 * LSTR];
    __shared__ unsigned short ehS[128 * LSTR];
    __shared__ unsigned short elS[128 * LSTR];
    __shared__ float nrmL[128];

    const int tid  = threadIdx.x;
    const int l    = tid & 63;
    const int w    = tid >> 6;
    const int j    = l >> 4;
    const int c16  = l & 15;
    const int base = blockIdx.x * 128;

    const float4* z4 = reinterpret_cast<const float4*>(z);
#pragma unroll
    for (int rep = 0; rep < 8; ++rep) {
        int flat = rep * 256 + tid;
        int pt   = flat >> 4;
        int dblk = flat & 15;
        int gp = base + pt; if (gp >= n) gp = n - 1;
        float4 v = z4[(size_t)gp * 16 + dblk];
        ushort4 h, lo;
        split2(v.x, h.x, lo.x); split2(v.y, h.y, lo.y);
        split2(v.z, h.z, lo.z); split2(v.w, h.w, lo.w);
        *reinterpret_cast<ushort4*>(&zhS[pt * LSTR + dblk * 4]) = h;
        *reinterpret_cast<ushort4*>(&zlS[pt * LSTR + dblk * 4]) = lo;
    }
    __syncthreads();

    short8v bzh[2][2], bzl[2][2];
#pragma unroll
    for (int p = 0; p < 2; ++p) {
        int pr = ((2 * w + p) * 16 + c16) * LSTR;
#pragma unroll
        for (int h = 0; h < 2; ++h) {
            int off = pr + h * 32 + j * 8;
            bzh[p][h] = *reinterpret_cast<const short8v*>(&zhS[off]);
            bzl[p][h] = *reinterpret_cast<const short8v*>(&zlS[off]);
        }
    }

    float m1[2] = {INFINITY, INFINITY};
    float m2[2] = {INFINITY, INFINITY};
    int   i1[2] = {0, 0};

    for (int c = 0; c < 4; ++c) {
        __syncthreads();
        const float4* cb4 = reinterpret_cast<const float4*>(cb);
#pragma unroll
        for (int rep = 0; rep < 8; ++rep) {
            int flat = rep * 256 + tid;
            int code = flat >> 4;
            int dblk = flat & 15;
            float4 v = cb4[(size_t)(c * 128 + code) * 16 + dblk];
            ushort4 h, lo;
            split2(v.x, h.x, lo.x); split2(v.y, h.y, lo.y);
            split2(v.z, h.z, lo.z); split2(v.w, h.w, lo.w);
            *reinterpret_cast<ushort4*>(&ehS[code * LSTR + dblk * 4]) = h;
            *reinterpret_cast<ushort4*>(&elS[code * LSTR + dblk * 4]) = lo;
        }
        if (tid < 32)
            reinterpret_cast<float4*>(nrmL)[tid] =
                reinterpret_cast<const float4*>(norms)[c * 32 + tid];
        __syncthreads();

#pragma unroll
        for (int ct = 0; ct < 8; ++ct) {
            int ar = (ct * 16 + c16) * LSTR + j * 8;
            short8v aeh0 = *reinterpret_cast<const short8v*>(&ehS[ar]);
            short8v aeh1 = *reinterpret_cast<const short8v*>(&ehS[ar + 32]);
            short8v ael0 = *reinterpret_cast<const short8v*>(&elS[ar]);
            short8v ael1 = *reinterpret_cast<const short8v*>(&elS[ar + 32]);
            float4 nr = *reinterpret_cast<const float4*>(&nrmL[ct * 16 + j * 4]);
            float nra[4] = {nr.x, nr.y, nr.z, nr.w};
            int kg0 = c * 128 + ct * 16 + j * 4;
#pragma unroll
            for (int p = 0; p < 2; ++p) {
                f32x4 acc = {0.f, 0.f, 0.f, 0.f};
                acc = __builtin_amdgcn_mfma_f32_16x16x32_bf16(aeh0, bzh[p][0], acc, 0, 0, 0);
                acc = __builtin_amdgcn_mfma_f32_16x16x32_bf16(aeh1, bzh[p][1], acc, 0, 0, 0);
                acc = __builtin_amdgcn_mfma_f32_16x16x32_bf16(aeh0, bzl[p][0], acc, 0, 0, 0);
                acc = __builtin_amdgcn_mfma_f32_16x16x32_bf16(aeh1, bzl[p][1], acc, 0, 0, 0);
                acc = __builtin_amdgcn_mfma_f32_16x16x32_bf16(ael0, bzh[p][0], acc, 0, 0, 0);
                acc = __builtin_amdgcn_mfma_f32_16x16x32_bf16(ael1, bzh[p][1], acc, 0, 0, 0);
#pragma unroll
                for (int r = 0; r < 4; ++r) {
                    float s = fmaf(-2.0f, acc[r], nra[r]);
                    int kg = kg0 + r;
                    bool lt1 = s < m1[p];
                    float nm2 = lt1 ? m1[p] : fminf(s, m2[p]);
                    i1[p] = lt1 ? kg : i1[p];
                    m1[p] = lt1 ? s : m1[p];
                    m2[p] = nm2;
                }
            }
        }
    }

#pragma unroll
    for (int p = 0; p < 2; ++p) {
        float a1 = m1[p], a2 = m2[p]; int ai = i1[p];
#pragma unroll
        for (int off = 16; off <= 32; off <<= 1) {
            float o1 = __shfl_xor(a1, off, 64);
            float o2 = __shfl_xor(a2, off, 64);
            int   oi = __shfl_xor(ai, off, 64);
            float hi = fmaxf(a1, o1);
            bool take = o1 < a1;
            ai = take ? oi : ai;
            a1 = take ? o1 : a1;
            a2 = fminf(hi, fminf(a2, o2));
        }
        int  ptg    = base + (2 * w + p) * 16 + c16;
        bool writer = (j == 0) && (ptg < n);
        bool flag   = writer && (a2 - a1 <= EPS_GAP);
        unsigned long long m = __ballot(flag);
        int abase = 0;
        if (m) {
            int leader = __ffsll(m) - 1;
            if (l == leader) abase = atomicAdd(cnt, __popcll(m));
            abase = __shfl(abase, leader, 64);
        }
        if (writer) {
            int val = ai;
            if (flag) {
                int rank = __popcll(m & ((1ull << l) - 1ull));
                int slot = abase + rank;
                if (slot < cap) list[slot] = ptg;
                else            val |= (int)0x80000000;
            }
            out[ptg] = val;
        }
    }
}

// ---------- Pass 2: one BLOCK (4 waves, 2 codes/lane) per flagged point ----------
__global__ __launch_bounds__(256)
void vq_cleanup_kernel(const float* __restrict__ z, const float* __restrict__ cb,
                       const float* __restrict__ norms,
                       const int* __restrict__ cnt, const int* __restrict__ list,
                       int cap, int* __restrict__ out, int n) {
    __shared__ float rbv[4];
    __shared__ int   rbi[4];
    const int tid  = threadIdx.x;
    const int lane = tid & 63;
    const int wv   = tid >> 6;

    int total = *cnt;
    int lim   = total < cap ? total : cap;

    for (int i = blockIdx.x; i < lim; i += gridDim.x) {
        int pt = list[i];
        float zr[D_DIM];
        const float4* zp = reinterpret_cast<const float4*>(z + (size_t)pt * D_DIM);
#pragma unroll
        for (int g = 0; g < 16; ++g) {
            float4 q = zp[g];
            zr[4*g+0]=q.x; zr[4*g+1]=q.y; zr[4*g+2]=q.z; zr[4*g+3]=q.w;
        }
        const float sz = np_sumsq64(zr);           // FROZEN tree
        float best = INFINITY; int bi = 0x7FFFFFFF;
#pragma unroll 1
        for (int r = 0; r < 2; ++r) {              // 2 codes/thread, sequential
            int k = tid * 2 + r;
            const float4* e4 = reinterpret_cast<const float4*>(cb) + ((size_t)k << 4);
            float a = 0.f;
#pragma unroll
            for (int g = 0; g < 16; ++g) {         // FROZEN ascending-d chain
                float4 q = e4[g];
                a = fmaf(zr[4*g+0], q.x, a);
                a = fmaf(zr[4*g+1], q.y, a);
                a = fmaf(zr[4*g+2], q.z, a);
                a = fmaf(zr[4*g+3], q.w, a);
            }
            float s = __fadd_rn(__fsub_rn(sz, __fmul_rn(2.0f, a)), norms[k]);
            if (s < best || (s == best && k < bi)) { best = s; bi = k; }
        }
#pragma unroll
        for (int off = 1; off < 64; off <<= 1) {   // wave (value,index) reduce
            float os = __shfl_xor(best, off, 64);
            int   ok = __shfl_xor(bi, off, 64);
            if (os < best || (os == best && ok < bi)) { best = os; bi = ok; }
        }
        if (lane == 0) { rbv[wv] = best; rbi[wv] = bi; }
        __syncthreads();
        if (tid == 0) {
            float b = rbv[0]; int id = rbi[0];
#pragma unroll
            for (int q = 1; q < 4; ++q) {
                float v = rbv[q]; int vi = rbi[q];
                if (v < b || (v == b && vi < id)) { b = v; id = vi; }
            }
            out[pt] = id;
        }
        __syncthreads();
    }

    // overflow fallback: wave-per-point scan of out[] for bit-31 flags
    if (total > cap) {
        const int wid    = (blockIdx.x * blockDim.x + tid) >> 6;
        const int nwaves = (gridDim.x * blockDim.x) >> 6;
        for (int b = wid * 64; b < n; b += nwaves * 64) {
            int t = b + lane;
            int v = (t < n) ? out[t] : 0;
            unsigned long long m = __ballot(v < 0);
            while (m) {
                int bb = __ffsll(m) - 1;
                m &= m - 1ull;
                int pt = b + bb;
                float zr[D_DIM];
                const float4* zp = reinterpret_cast<const float4*>(z + (size_t)pt * D_DIM);
#pragma unroll
                for (int g = 0; g < 16; ++g) {
                    float4 q = zp[g];
                    zr[4*g+0]=q.x; zr[4*g+1]=q.y; zr[4*g+2]=q.z; zr[4*g+3]=q.w;
                }
                const float sz = np_sumsq64(zr);
                float best = INFINITY; int bi = 0x7FFFFFFF;
#pragma unroll 1
                for (int r = 0; r < 8; ++r) {
                    const float4* e4 = reinterpret_cast<const float4*>(cb) +
                                       ((size_t)(lane * 8 + r) << 4);
                    float a = 0.f;
#pragma unroll
                    for (int g = 0; g < 16; ++g) {
                        float4 q = e4[g];
                        a = fmaf(zr[4*g+0], q.x, a);
                        a = fmaf(zr[4*g+1], q.y, a);
                        a = fmaf(zr[4*g+2], q.z, a);
                        a = fmaf(zr[4*g+3], q.w, a);
                    }
                    float s = __fadd_rn(__fsub_rn(sz, __fmul_rn(2.0f, a)),
                                        norms[lane * 8 + r]);
                    if (s < best) { best = s; bi = lane * 8 + r; }
                }
#pragma unroll
                for (int off = 1; off < 64; off <<= 1) {
                    float os = __shfl_xor(best, off, 64);
                    int   ok = __shfl_xor(bi, off, 64);
                    if (os < best || (os == best && ok < bi)) { best = os; bi = ok; }
                }
                if (lane == 0) out[pt] = bi;
            }
        }
    }
}

extern "C" void kernel_launch(void* const* d_in, const int* in_sizes, int n_in,
                              void* d_out, int out_size, void* d_ws, size_t ws_size,
                              hipStream_t stream) {
    const float* z  = (const float*)d_in[0];
    const float* cb = (const float*)d_in[1];
    int n = in_sizes[0] / D_DIM;           // 131072 points
    float* norms = (float*)d_ws;
    int*   cnt   = (int*)((char*)d_ws + WS_CNT_OFF);
    int* out = (int*)d_out;

    bool fast = ws_size >= (size_t)WS_LIST_OFF + 4096;
    vq_prep_kernel<<<(4 * K_CODES + 255) / 256, 256, 0, stream>>>(cb, norms, fast ? 1 : 0);

    if (fast) {
        const unsigned short* eh = (const unsigned short*)((char*)d_ws + WS_EH_OFF);
        const unsigned short* el = (const unsigned short*)((char*)d_ws + WS_EL_OFF);
        int* list = (int*)((char*)d_ws + WS_LIST_OFF);
        int  cap  = (int)((ws_size - WS_LIST_OFF) / 4);
        vq_pass1_mono<<<(n + BM - 1) / BM, THREADS, 0, stream>>>(
            z, eh, el, norms, out, cnt, list, cap, n);
        vq_cleanup_kernel<<<2048, 256, 0, stream>>>(z, cb, norms, cnt, list, cap, out, n);
    } else {
        int* list = (int*)d_ws + 513;
        int  cap  = (int)(ws_size / 4) - 513; if (cap < 0) cap = 0;
        vq_pass1_legacy<<<(n + 127) / 128, 256, 0, stream>>>(
            z, cb, norms, out, cnt, list, cap, n);
        vq_cleanup_kernel<<<2048, 256, 0, stream>>>(z, cb, norms, cnt, list, cap, out, n);
    }
}